// Round 1
// baseline (8572.583 us; speedup 1.0000x reference)
//
#include <hip/hip_runtime.h>
#include <math.h>

#define H 8
#define DK 32
#define NHID 256
#define LNUM 2
#define GNUM 16

// ---------- float <-> ordered-uint encoding for atomicMax on floats ----------
__device__ __forceinline__ unsigned encf(float f) {
    unsigned u = __float_as_uint(f);
    return (u & 0x80000000u) ? ~u : (u | 0x80000000u);
}
__device__ __forceinline__ float decf(unsigned u) {
    return __uint_as_float((u & 0x80000000u) ? (u ^ 0x80000000u) : ~u);
}

// ---------- temporal encoding table: te7[t][j] = time_tab[t] @ time_w + time_b, t<7 ----------
__global__ void te_kernel(const float* __restrict__ time_tab, const float* __restrict__ time_w,
                          const float* __restrict__ time_b, float* __restrict__ te7) {
    int t = threadIdx.x >> 5, j = threadIdx.x & 31;
    if (t < 7) {
        float s = time_b[j];
        #pragma unroll
        for (int i = 0; i < 32; ++i) s += time_tab[t * 32 + i] * time_w[i * 32 + j];
        te7[t * 32 + j] = s;
    }
}

// ---------- gather rows (topic init) ----------
__global__ void gather_rows(const float* __restrict__ emb, const int* __restrict__ idx,
                            float* __restrict__ out, int n) {
    int row = blockIdx.x, c = threadIdx.x;
    if (row < n) out[(size_t)row * 256 + c] = emb[(size_t)idx[row] * 256 + c];
}

// ---------- broadcast one row (doc init) ----------
__global__ void bcast_row(const float* __restrict__ src, float* __restrict__ out, int n) {
    int row = blockIdx.x, c = threadIdx.x;
    if (row < n) out[(size_t)row * 256 + c] = src[c];
}

// ---------- GEMM: C[n,256] = (gather(A)[n,256] * inScale) @ W[256,256] + bias ----------
// 64x64 tile per block, 256 threads, 4x4 register blocking.
__global__ __launch_bounds__(256) void gemm_n256(
    const float* __restrict__ A, const int* __restrict__ gidx,
    const float* __restrict__ W, const float* __restrict__ bias,
    float* __restrict__ C, int n, float inScale)
{
    __shared__ float As[64 * 17];   // [row][k] stride 17 (bank-conflict pad)
    __shared__ float Ws[16 * 64];   // [kk][col]
    const int tid = threadIdx.x;
    const int rowBase = blockIdx.x * 64;
    const int colBase = blockIdx.y * 64;
    const int cx = tid & 15, ry = tid >> 4;
    const int lkk = tid & 15, lrg = tid >> 4;       // A-load mapping
    const int wk = tid >> 4, wc4 = (tid & 15) * 4;  // W-load mapping
    float acc[4][4] = {{0.f}};

    for (int kb = 0; kb < 16; ++kb) {
        #pragma unroll
        for (int u = 0; u < 4; ++u) {
            int r = rowBase + lrg * 4 + u;
            float v = 0.f;
            if (r < n) {
                int rr = gidx ? gidx[r] : r;
                v = A[(size_t)rr * 256 + kb * 16 + lkk] * inScale;
            }
            As[(lrg * 4 + u) * 17 + lkk] = v;
        }
        {
            const float4 wv = *reinterpret_cast<const float4*>(
                &W[(size_t)(kb * 16 + wk) * 256 + colBase + wc4]);
            *reinterpret_cast<float4*>(&Ws[wk * 64 + wc4]) = wv;
        }
        __syncthreads();
        #pragma unroll
        for (int kk = 0; kk < 16; ++kk) {
            float a0 = As[(ry * 4 + 0) * 17 + kk];
            float a1 = As[(ry * 4 + 1) * 17 + kk];
            float a2 = As[(ry * 4 + 2) * 17 + kk];
            float a3 = As[(ry * 4 + 3) * 17 + kk];
            const float4 wv = *reinterpret_cast<const float4*>(&Ws[kk * 64 + cx * 4]);
            acc[0][0] += a0 * wv.x; acc[0][1] += a0 * wv.y; acc[0][2] += a0 * wv.z; acc[0][3] += a0 * wv.w;
            acc[1][0] += a1 * wv.x; acc[1][1] += a1 * wv.y; acc[1][2] += a1 * wv.z; acc[1][3] += a1 * wv.w;
            acc[2][0] += a2 * wv.x; acc[2][1] += a2 * wv.y; acc[2][2] += a2 * wv.z; acc[2][3] += a2 * wv.w;
            acc[3][0] += a3 * wv.x; acc[3][1] += a3 * wv.y; acc[3][2] += a3 * wv.z; acc[3][3] += a3 * wv.w;
        }
        __syncthreads();
    }
    #pragma unroll
    for (int u = 0; u < 4; ++u) {
        int r = rowBase + ry * 4 + u;
        if (r < n) {
            int c = colBase + cx * 4;
            float4 o;
            o.x = acc[u][0] + bias[c + 0];
            o.y = acc[u][1] + bias[c + 1];
            o.z = acc[u][2] + bias[c + 2];
            o.w = acc[u][3] + bias[c + 3];
            *reinterpret_cast<float4*>(&C[(size_t)r * 256 + c]) = o;
        }
    }
}

// ---------- EK1: edge logits a = (q[dst] . (k[src] @ attR)) * pri / sqrt(DK); atomicMax per (dst,h) ----------
__global__ __launch_bounds__(256) void ek1_logits(
    const float* __restrict__ kbuf, const float* __restrict__ qbuf,
    const int* __restrict__ src, const int* __restrict__ dst,
    const float* __restrict__ attR /* [8][32][32] pre-offset */,
    const float* __restrict__ pri  /* [8] pre-offset */,
    float* __restrict__ alog, unsigned* __restrict__ mmax, int E)
{
    __shared__ float aR[8 * 1028];  // per-head stride 1028 words: banks 4h distinct
    for (int i = threadIdx.x; i < 8192; i += 256) {
        int hh = i >> 10, rem = i & 1023;
        aR[hh * 1028 + rem] = attR[i];
    }
    __syncthreads();
    int gid = blockIdx.x * 256 + threadIdx.x;
    int e = gid >> 3, h = gid & 7;
    if (e >= E) return;
    int s = src[e], d = dst[e];
    const float* kv = kbuf + (size_t)s * 256 + h * 32;
    const float* qv = qbuf + (size_t)d * 256 + h * 32;
    float key[32];
    #pragma unroll
    for (int l = 0; l < 32; ++l) key[l] = 0.f;
    #pragma unroll
    for (int k = 0; k < 32; ++k) {
        float kk = kv[k];
        const float* ar = &aR[h * 1028 + k * 32];
        #pragma unroll
        for (int l = 0; l < 32; ++l) key[l] += kk * ar[l];
    }
    float a = 0.f;
    #pragma unroll
    for (int l = 0; l < 32; ++l) a += qv[l] * key[l];
    a *= pri[h] * 0.17677669529663687f;  // 1/sqrt(32)
    alog[(size_t)e * 8 + h] = a;
    atomicMax(&mmax[(size_t)d * 8 + h], encf(a));
}

// ---------- EK2: ex = exp(a - m[dst]); den[dst,h] += ex ----------
__global__ void ek2_expsum(const int* __restrict__ dst, float* __restrict__ alog,
                           const unsigned* __restrict__ mmax, float* __restrict__ den, int E) {
    int gid = blockIdx.x * 256 + threadIdx.x;
    int e = gid >> 3, h = gid & 7;
    if (e >= E) return;
    int d = dst[e];
    float m = decf(mmax[(size_t)d * 8 + h]);
    float ex = expf(alog[(size_t)e * 8 + h] - m);
    alog[(size_t)e * 8 + h] = ex;
    atomicAdd(&den[(size_t)d * 8 + h], ex);
}

// ---------- EK3: he[dst] += (ex/den) * (v[src] @ msgR + te) ----------
__global__ __launch_bounds__(256) void ek3_agg(
    const float* __restrict__ vbuf, const int* __restrict__ src, const int* __restrict__ dst,
    const int* __restrict__ timeIdx, const float* __restrict__ msgR /* pre-offset */,
    const float* __restrict__ te7, const float* __restrict__ alog,
    const float* __restrict__ den, float* __restrict__ he, int E)
{
    __shared__ float mR[8 * 1028];
    __shared__ float sTe[224];
    for (int i = threadIdx.x; i < 8192; i += 256) {
        int hh = i >> 10, rem = i & 1023;
        mR[hh * 1028 + rem] = msgR[i];
    }
    if (threadIdx.x < 224) sTe[threadIdx.x] = te7[threadIdx.x];
    __syncthreads();
    int gid = blockIdx.x * 256 + threadIdx.x;
    int e = gid >> 3, h = gid & 7;
    if (e >= E) return;
    int s = src[e], d = dst[e];
    float w = alog[(size_t)e * 8 + h] / fmaxf(den[(size_t)d * 8 + h], 1e-9f);
    const float* vv = vbuf + (size_t)s * 256 + h * 32;
    float val[32];
    #pragma unroll
    for (int l = 0; l < 32; ++l) val[l] = 0.f;
    #pragma unroll
    for (int k = 0; k < 32; ++k) {
        float vk = vv[k];
        const float* mr = &mR[h * 1028 + k * 32];
        #pragma unroll
        for (int l = 0; l < 32; ++l) val[l] += vk * mr[l];
    }
    if (timeIdx) {
        int t = timeIdx[e];
        #pragma unroll
        for (int l = 0; l < 32; ++l) val[l] += sTe[t * 32 + l];
    }
    float* hp = he + (size_t)d * 256 + h * 32;
    #pragma unroll
    for (int l = 0; l < 32; ++l) atomicAdd(&hp[l], w * val[l]);
}

// ---------- EK4: t += relu(he); he = 0 ----------
__global__ void ek4_relu_acc(float* __restrict__ t, float* __restrict__ he, int total) {
    int i = blockIdx.x * 256 + threadIdx.x;
    if (i < total) {
        float x = he[i];
        he[i] = 0.f;
        t[i] += fmaxf(x, 0.f);
    }
}

// ---------- skip-mix + layernorm (in-place on h) ----------
__global__ __launch_bounds__(256) void mix_ln(
    float* __restrict__ h, const float* __restrict__ trans, const float* __restrict__ skipP,
    const float* __restrict__ g, const float* __restrict__ b, int n)
{
    int row = blockIdx.x;
    if (row >= n) return;
    int c = threadIdx.x;
    float alpha = 1.f / (1.f + expf(-skipP[0]));
    size_t off = (size_t)row * 256 + c;
    float o = trans[off] * alpha + h[off] * (1.f - alpha);
    float s = o, ss = o * o;
    #pragma unroll
    for (int d = 1; d < 64; d <<= 1) { s += __shfl_xor(s, d); ss += __shfl_xor(ss, d); }
    __shared__ float rS[4], rSS[4];
    int w = threadIdx.x >> 6, lane = threadIdx.x & 63;
    if (lane == 0) { rS[w] = s; rSS[w] = ss; }
    __syncthreads();
    float S = rS[0] + rS[1] + rS[2] + rS[3];
    float SS = rSS[0] + rSS[1] + rSS[2] + rSS[3];
    float mean = S * (1.f / 256.f);
    float var = fmaxf(SS * (1.f / 256.f) - mean * mean, 0.f);
    float rs = rsqrtf(var + 1e-5f);
    h[off] = (o - mean) * rs * g[c] + b[c];
}

// ---------- group max (encoded atomicMax) ----------
__global__ void gmax_enc(const float* __restrict__ h, const int* __restrict__ grp,
                         unsigned* __restrict__ gi, int n, int colBase) {
    int row = blockIdx.x, c = threadIdx.x;
    if (row < n) atomicMax(&gi[grp[row] * 768 + colBase + c], encf(h[(size_t)row * 256 + c]));
}

// ---------- final: logits, loss, sigmoid ----------
__global__ __launch_bounds__(1024) void final_k(const unsigned* __restrict__ gi,
                                                const float* __restrict__ out_w,
                                                const float* __restrict__ out_b,
                                                const float* __restrict__ y,
                                                float* __restrict__ out) {
    int w = threadIdx.x >> 6, lane = threadIdx.x & 63;
    float s = 0.f;
    for (int c = lane; c < 768; c += 64) s += decf(gi[w * 768 + c]) * out_w[c];
    #pragma unroll
    for (int d = 1; d < 64; d <<= 1) s += __shfl_xor(s, d);
    __shared__ float lloss[16];
    if (lane == 0) {
        float z = s + out_b[0];
        out[1 + w] = 1.f / (1.f + expf(-z));
        lloss[w] = fmaxf(z, 0.f) - z * y[w] + log1pf(expf(-fabsf(z)));
    }
    __syncthreads();
    if (threadIdx.x == 0) {
        float L = 0.f;
        for (int g2 = 0; g2 < 16; ++g2) L += lloss[g2];
        out[0] = L * (1.f / 16.f);
    }
}

extern "C" void kernel_launch(void* const* d_in, const int* in_sizes, int n_in,
                              void* d_out, int out_size, void* d_ws, size_t ws_size,
                              hipStream_t stream) {
    // ---- inputs (setup_inputs dict order) ----
    const int* word_id   = (const int*)d_in[0];
    const int* topic_id  = (const int*)d_in[1];
    const int* g_word    = (const int*)d_in[2];
    const int* g_topic   = (const int*)d_in[3];
    const int* g_doc     = (const int*)d_in[4];
    const int* src_ww = (const int*)d_in[5];  const int* dst_ww = (const int*)d_in[6];  const int* time_ww = (const int*)d_in[7];
    const int* src_wd = (const int*)d_in[8];  const int* dst_wd = (const int*)d_in[9];  const int* time_wd = (const int*)d_in[10];
    const int* src_wt = (const int*)d_in[11]; const int* dst_wt = (const int*)d_in[12]; const int* time_wt = (const int*)d_in[13];
    const int* src_td = (const int*)d_in[14]; const int* dst_td = (const int*)d_in[15]; const int* time_td = (const int*)d_in[16];
    const int* src_tt = (const int*)d_in[17]; const int* dst_tt = (const int*)d_in[18];
    const float* y_data      = (const float*)d_in[19];
    const float* word_embeds = (const float*)d_in[20];
    const float* topic_embeds= (const float*)d_in[21];
    const float* doc_gen     = (const float*)d_in[22];
    const float* adapt_w     = (const float*)d_in[23];
    const float* adapt_b     = (const float*)d_in[24];
    const float* time_tab    = (const float*)d_in[25];
    const float* time_w      = (const float*)d_in[26];
    const float* time_b      = (const float*)d_in[27];
    const float* kW = (const float*)d_in[28];
    const float* qW = (const float*)d_in[29];
    const float* vW = (const float*)d_in[30];
    const float* aW = (const float*)d_in[31];
    const float* kB = (const float*)d_in[32];
    const float* qB = (const float*)d_in[33];
    const float* vB = (const float*)d_in[34];
    const float* aB = (const float*)d_in[35];
    const float* skip = (const float*)d_in[36];
    const float* ln_g = (const float*)d_in[37];
    const float* ln_b = (const float*)d_in[38];
    const float* pri  = (const float*)d_in[39];
    const float* attR = (const float*)d_in[40];
    const float* msgR = (const float*)d_in[41];
    const float* out_w = (const float*)d_in[42];
    const float* out_b = (const float*)d_in[43];

    const int NW = in_sizes[0], NT = in_sizes[1], ND = in_sizes[4];
    const int E_ww = in_sizes[5], E_wd = in_sizes[8], E_wt = in_sizes[11],
              E_td = in_sizes[14], E_tt = in_sizes[17];
    const int nN[3] = {NW, NT, ND};
    const float invNin[3] = {1.f / 3.f, 1.f / 3.f, 1.f / 2.f};

    // ---- workspace carve-up ----
    float* base = (float*)d_ws;
    size_t off = 0;
    auto take = [&](size_t nElems) { float* p = base + off; off += (nElems + 63) & ~(size_t)63; return p; };
    float* hP[3]; float* kP[3]; float* qP[3]; float* vP[3]; float* tP[3];
    for (int i = 0; i < 3; ++i) hP[i] = take((size_t)nN[i] * 256);
    for (int i = 0; i < 3; ++i) kP[i] = take((size_t)nN[i] * 256);
    for (int i = 0; i < 3; ++i) qP[i] = take((size_t)nN[i] * 256);
    for (int i = 0; i < 3; ++i) vP[i] = take((size_t)nN[i] * 256);
    for (int i = 0; i < 3; ++i) tP[i] = take((size_t)nN[i] * 256);
    float* he   = take((size_t)NW * 256);      // per-etype aggregate / trans scratch
    float* alog = take((size_t)E_ww * 8);      // E_ww is the max edge count
    float* den  = take((size_t)NW * 8);
    unsigned* mmax = (unsigned*)take((size_t)NW * 8);
    float* te7  = take(7 * 32);
    unsigned* gi = (unsigned*)take(16 * 768);
    (void)ws_size; (void)n_in; (void)out_size;

    struct Rel { int e, s, d; const int* src; const int* dst; const int* tim; int E; };
    const Rel rels[8] = {
        {0, 0, 1, src_wt, dst_wt, time_wt, E_wt},
        {1, 0, 2, src_wd, dst_wd, time_wd, E_wd},
        {2, 1, 2, src_td, dst_td, time_td, E_td},
        {3, 1, 1, src_tt, dst_tt, nullptr, E_tt},
        {4, 0, 0, src_ww, dst_ww, time_ww, E_ww},
        {5, 1, 0, dst_wt, src_wt, time_wt, E_wt},
        {6, 2, 1, dst_td, src_td, time_td, E_td},
        {7, 2, 0, dst_wd, src_wd, time_wd, E_wd},
    };

    // ---- temporal table ----
    te_kernel<<<1, 256, 0, stream>>>(time_tab, time_w, time_b, te7);

    // ---- init node features ----
    {
        dim3 g((NW + 63) / 64, 4);
        gemm_n256<<<g, 256, 0, stream>>>(word_embeds, word_id, adapt_w, adapt_b, hP[0], NW, 1.f);
    }
    gather_rows<<<NT, 256, 0, stream>>>(topic_embeds, topic_id, hP[1], NT);
    bcast_row<<<ND, 256, 0, stream>>>(doc_gen, hP[2], ND);

    // ---- layers ----
    for (int li = 0; li < LNUM; ++li) {
        for (int i = 0; i < 3; ++i)
            hipMemsetAsync(tP[i], 0, (size_t)nN[i] * 256 * sizeof(float), stream);
        hipMemsetAsync(he, 0, (size_t)NW * 256 * sizeof(float), stream);

        for (int i = 0; i < 3; ++i) {
            dim3 g((nN[i] + 63) / 64, 4);
            size_t wOff = ((size_t)li * 3 + i) * 65536;
            size_t bOff = ((size_t)li * 3 + i) * 256;
            gemm_n256<<<g, 256, 0, stream>>>(hP[i], nullptr, kW + wOff, kB + bOff, kP[i], nN[i], 1.f);
            gemm_n256<<<g, 256, 0, stream>>>(hP[i], nullptr, qW + wOff, qB + bOff, qP[i], nN[i], 1.f);
            gemm_n256<<<g, 256, 0, stream>>>(hP[i], nullptr, vW + wOff, vB + bOff, vP[i], nN[i], 1.f);
        }

        for (int r = 0; r < 8; ++r) {
            const Rel& R = rels[r];
            int nD = nN[R.d];
            hipMemsetAsync(mmax, 0, (size_t)nD * 8 * sizeof(unsigned), stream);
            hipMemsetAsync(den, 0, (size_t)nD * 8 * sizeof(float), stream);
            int egrid = (R.E * 8 + 255) / 256;
            size_t rOff = ((size_t)li * 8 + R.e) * 8192;
            size_t pOff = ((size_t)li * 8 + R.e) * 8;
            ek1_logits<<<egrid, 256, 0, stream>>>(kP[R.s], qP[R.d], R.src, R.dst,
                                                  attR + rOff, pri + pOff, alog, mmax, R.E);
            ek2_expsum<<<egrid, 256, 0, stream>>>(R.dst, alog, mmax, den, R.E);
            ek3_agg<<<egrid, 256, 0, stream>>>(vP[R.s], R.src, R.dst, R.tim,
                                               msgR + rOff, te7, alog, den, he, R.E);
            ek4_relu_acc<<<nD, 256, 0, stream>>>(tP[R.d], he, nD * 256);
        }

        for (int i = 0; i < 3; ++i) {
            dim3 g((nN[i] + 63) / 64, 4);
            size_t wOff = ((size_t)li * 3 + i) * 65536;
            size_t bOff = ((size_t)li * 3 + i) * 256;
            gemm_n256<<<g, 256, 0, stream>>>(tP[i], nullptr, aW + wOff, aB + bOff, he, nN[i], invNin[i]);
            mix_ln<<<nN[i], 256, 0, stream>>>(hP[i], he, skip + ((size_t)li * 3 + i),
                                              ln_g + bOff, ln_b + bOff, nN[i]);
        }
        // NOTE: `he` now holds the last trans; re-zeroed at next layer start.
    }

    // ---- readout: group max -> logits -> loss/sigmoid ----
    hipMemsetAsync(gi, 0, 16 * 768 * sizeof(unsigned), stream);
    gmax_enc<<<ND, 256, 0, stream>>>(hP[2], g_doc, gi, ND, 0);
    gmax_enc<<<NW, 256, 0, stream>>>(hP[0], g_word, gi, NW, 256);
    gmax_enc<<<NT, 256, 0, stream>>>(hP[1], g_topic, gi, NT, 512);
    final_k<<<1, 1024, 0, stream>>>(gi, out_w, out_b, y_data, (float*)d_out);
}

// Round 2
// 2443.221 us; speedup vs baseline: 3.5087x; 3.5087x over previous
//
#include <hip/hip_runtime.h>
#include <hip/hip_bf16.h>
#include <math.h>

#define H 8
#define DK 32
#define NHID 256
#define LNUM 2
#define GNUM 16

// ---------- float <-> ordered-uint encoding for atomicMax on floats ----------
__device__ __forceinline__ unsigned encf(float f) {
    unsigned u = __float_as_uint(f);
    return (u & 0x80000000u) ? ~u : (u | 0x80000000u);
}
__device__ __forceinline__ float decf(unsigned u) {
    return __uint_as_float((u & 0x80000000u) ? (u ^ 0x80000000u) : ~u);
}
__device__ __forceinline__ float bfd(unsigned short u) {
    return __uint_as_float(((unsigned)u) << 16);
}
__device__ __forceinline__ unsigned short f2bf(float x) {
    __hip_bfloat16 b = __float2bfloat16(x);
    return *reinterpret_cast<unsigned short*>(&b);
}

// ---------- temporal encoding table ----------
__global__ void te_kernel(const float* __restrict__ time_tab, const float* __restrict__ time_w,
                          const float* __restrict__ time_b, float* __restrict__ te7) {
    int t = threadIdx.x >> 5, j = threadIdx.x & 31;
    if (t < 7) {
        float s = time_b[j];
        #pragma unroll
        for (int i = 0; i < 32; ++i) s += time_tab[t * 32 + i] * time_w[i * 32 + j];
        te7[t * 32 + j] = s;
    }
}

__global__ void gather_rows(const float* __restrict__ emb, const int* __restrict__ idx,
                            float* __restrict__ out, int n) {
    int row = blockIdx.x, c = threadIdx.x;
    if (row < n) out[(size_t)row * 256 + c] = emb[(size_t)idx[row] * 256 + c];
}

__global__ void bcast_row(const float* __restrict__ src, float* __restrict__ out, int n) {
    int row = blockIdx.x, c = threadIdx.x;
    if (row < n) out[(size_t)row * 256 + c] = src[c];
}

// ---------- GEMM: C[n,256] = (gather(A)[n,256] * inScale) @ W[256,256] + bias ----------
__global__ __launch_bounds__(256) void gemm_n256(
    const float* __restrict__ A, const int* __restrict__ gidx,
    const float* __restrict__ W, const float* __restrict__ bias,
    float* __restrict__ C, int n, float inScale)
{
    __shared__ float As[64 * 17];
    __shared__ float Ws[16 * 64];
    const int tid = threadIdx.x;
    const int rowBase = blockIdx.x * 64;
    const int colBase = blockIdx.y * 64;
    const int cx = tid & 15, ry = tid >> 4;
    const int lkk = tid & 15, lrg = tid >> 4;
    const int wk = tid >> 4, wc4 = (tid & 15) * 4;
    float acc[4][4] = {{0.f}};

    for (int kb = 0; kb < 16; ++kb) {
        #pragma unroll
        for (int u = 0; u < 4; ++u) {
            int r = rowBase + lrg * 4 + u;
            float v = 0.f;
            if (r < n) {
                int rr = gidx ? gidx[r] : r;
                v = A[(size_t)rr * 256 + kb * 16 + lkk] * inScale;
            }
            As[(lrg * 4 + u) * 17 + lkk] = v;
        }
        {
            const float4 wv = *reinterpret_cast<const float4*>(
                &W[(size_t)(kb * 16 + wk) * 256 + colBase + wc4]);
            *reinterpret_cast<float4*>(&Ws[wk * 64 + wc4]) = wv;
        }
        __syncthreads();
        #pragma unroll
        for (int kk = 0; kk < 16; ++kk) {
            float a0 = As[(ry * 4 + 0) * 17 + kk];
            float a1 = As[(ry * 4 + 1) * 17 + kk];
            float a2 = As[(ry * 4 + 2) * 17 + kk];
            float a3 = As[(ry * 4 + 3) * 17 + kk];
            const float4 wv = *reinterpret_cast<const float4*>(&Ws[kk * 64 + cx * 4]);
            acc[0][0] += a0 * wv.x; acc[0][1] += a0 * wv.y; acc[0][2] += a0 * wv.z; acc[0][3] += a0 * wv.w;
            acc[1][0] += a1 * wv.x; acc[1][1] += a1 * wv.y; acc[1][2] += a1 * wv.z; acc[1][3] += a1 * wv.w;
            acc[2][0] += a2 * wv.x; acc[2][1] += a2 * wv.y; acc[2][2] += a2 * wv.z; acc[2][3] += a2 * wv.w;
            acc[3][0] += a3 * wv.x; acc[3][1] += a3 * wv.y; acc[3][2] += a3 * wv.z; acc[3][3] += a3 * wv.w;
        }
        __syncthreads();
    }
    #pragma unroll
    for (int u = 0; u < 4; ++u) {
        int r = rowBase + ry * 4 + u;
        if (r < n) {
            int c = colBase + cx * 4;
            float4 o;
            o.x = acc[u][0] + bias[c + 0];
            o.y = acc[u][1] + bias[c + 1];
            o.z = acc[u][2] + bias[c + 2];
            o.w = acc[u][3] + bias[c + 3];
            *reinterpret_cast<float4*>(&C[(size_t)r * 256 + c]) = o;
        }
    }
}

// ---------- block-diagonal per-head transform: out[n,h*32+l] = sum_k in[n,h*32+k]*R[h,k,l], bf16 out ----------
__global__ __launch_bounds__(256) void bd_gemm(
    const float* __restrict__ in, const float* __restrict__ R /* [8][32][32] pre-offset */,
    unsigned short* __restrict__ out, int n)
{
    __shared__ float As[64 * 33];
    __shared__ float Rs[32 * 33];
    const int tid = threadIdx.x;
    const int head = blockIdx.y;
    const int rowBase = blockIdx.x * 64;
    {   // load A tile: 64 rows x 32 k
        int row = tid >> 2, q = tid & 3;
        int r = rowBase + row;
        float4 a0 = make_float4(0, 0, 0, 0), a1 = make_float4(0, 0, 0, 0);
        if (r < n) {
            const float4* p = reinterpret_cast<const float4*>(in + (size_t)r * 256 + head * 32 + q * 8);
            a0 = p[0]; a1 = p[1];
        }
        float* ap = &As[row * 33 + q * 8];
        ap[0] = a0.x; ap[1] = a0.y; ap[2] = a0.z; ap[3] = a0.w;
        ap[4] = a1.x; ap[5] = a1.y; ap[6] = a1.z; ap[7] = a1.w;
    }
    {   // load R: 32x32
        int k = tid >> 3, l0 = (tid & 7) * 4;
        float4 rv = *reinterpret_cast<const float4*>(R + head * 1024 + k * 32 + l0);
        float* rp = &Rs[k * 33 + l0];
        rp[0] = rv.x; rp[1] = rv.y; rp[2] = rv.z; rp[3] = rv.w;
    }
    __syncthreads();
    const int wv = tid >> 6, lane = tid & 63;
    float acc[8] = {0.f, 0.f, 0.f, 0.f, 0.f, 0.f, 0.f, 0.f};
    #pragma unroll
    for (int k = 0; k < 32; ++k) {
        float a = As[lane * 33 + k];
        const float* rp = &Rs[k * 33 + wv * 8];
        #pragma unroll
        for (int j = 0; j < 8; ++j) acc[j] += a * rp[j];
    }
    int r = rowBase + lane;
    if (r < n) {
        ushort4 o0, o1;
        o0.x = f2bf(acc[0]); o0.y = f2bf(acc[1]); o0.z = f2bf(acc[2]); o0.w = f2bf(acc[3]);
        o1.x = f2bf(acc[4]); o1.y = f2bf(acc[5]); o1.z = f2bf(acc[6]); o1.w = f2bf(acc[7]);
        ushort4* po = reinterpret_cast<ushort4*>(out + (size_t)r * 256 + head * 32 + wv * 8);
        po[0] = o0; po[1] = o1;
    }
}

// ---------- EK1: a = dot(q[dst][h], katt[src][h]) * pri / sqrt(DK); store + atomicMax ----------
__global__ __launch_bounds__(256) void ek1b(
    const float* __restrict__ qbuf, const unsigned short* __restrict__ katt,
    const int* __restrict__ src, const int* __restrict__ dst,
    const float* __restrict__ pri, float* __restrict__ alog, unsigned* __restrict__ mmax, int E)
{
    int gid = blockIdx.x * 256 + threadIdx.x;
    int e = gid >> 3, h = gid & 7;
    if (e >= E) return;
    int s = src[e], d = dst[e];
    const float4* q4 = reinterpret_cast<const float4*>(qbuf + (size_t)d * 256 + h * 32);
    const ushort4* k4 = reinterpret_cast<const ushort4*>(katt + (size_t)s * 256 + h * 32);
    float a = 0.f;
    #pragma unroll
    for (int j = 0; j < 8; ++j) {
        float4 q = q4[j]; ushort4 k = k4[j];
        a += q.x * bfd(k.x) + q.y * bfd(k.y) + q.z * bfd(k.z) + q.w * bfd(k.w);
    }
    a *= pri[h] * 0.17677669529663687f;
    alog[(size_t)e * 8 + h] = a;
    atomicMax(&mmax[(size_t)d * 8 + h], encf(a));
}

// ---------- EK2: ex = exp(a - m[dst]); den += ex ----------
__global__ void ek2_expsum(const int* __restrict__ dst, float* __restrict__ alog,
                           const unsigned* __restrict__ mmax, float* __restrict__ den, int E) {
    int gid = blockIdx.x * 256 + threadIdx.x;
    int e = gid >> 3, h = gid & 7;
    if (e >= E) return;
    int d = dst[e];
    float m = decf(mmax[(size_t)d * 8 + h]);
    float ex = expf(alog[(size_t)e * 8 + h] - m);
    alog[(size_t)e * 8 + h] = ex;
    atomicAdd(&den[(size_t)d * 8 + h], ex);
}

// ---------- EK3 (CSR): per-dst wave aggregation, fused relu accumulate, no atomics ----------
__global__ __launch_bounds__(256) void ek3_csr(
    const unsigned short* __restrict__ vmsg, const int* __restrict__ src, const int* __restrict__ tim,
    const int* __restrict__ rowptr, const int* __restrict__ eidx,
    const float* __restrict__ te7, const float* __restrict__ alog, const float* __restrict__ den,
    float* __restrict__ tacc, int nD)
{
    __shared__ float sTe[224];
    if (threadIdx.x < 224) sTe[threadIdx.x] = te7[threadIdx.x];
    __syncthreads();
    int wv = threadIdx.x >> 6, lane = threadIdx.x & 63;
    int d = blockIdx.x * 4 + wv;
    if (d >= nD) return;
    int beg = rowptr[d], end = rowptr[d + 1];
    if (beg == end) return;
    int c = lane * 4, h = lane >> 3;
    float invden = 1.f / fmaxf(den[(size_t)d * 8 + h], 1e-9f);
    float a0 = 0.f, a1 = 0.f, a2 = 0.f, a3 = 0.f;
    for (int p = beg; p < end; ++p) {
        int e = eidx[p], s = src[e];
        float w = alog[(size_t)e * 8 + h] * invden;
        ushort4 v = *reinterpret_cast<const ushort4*>(vmsg + (size_t)s * 256 + c);
        float vx = bfd(v.x), vy = bfd(v.y), vz = bfd(v.z), vw = bfd(v.w);
        if (tim) {
            const float* tp = &sTe[tim[e] * 32 + (c & 31)];
            vx += tp[0]; vy += tp[1]; vz += tp[2]; vw += tp[3];
        }
        a0 += w * vx; a1 += w * vy; a2 += w * vz; a3 += w * vw;
    }
    float4* tp4 = reinterpret_cast<float4*>(tacc + (size_t)d * 256 + c);
    float4 o = *tp4;
    o.x += fmaxf(a0, 0.f); o.y += fmaxf(a1, 0.f); o.z += fmaxf(a2, 0.f); o.w += fmaxf(a3, 0.f);
    *tp4 = o;
}

// ---------- CSR build ----------
__global__ void count_k(const int* __restrict__ dst, int* __restrict__ cnt, int E) {
    int e = blockIdx.x * 256 + threadIdx.x;
    if (e < E) atomicAdd(&cnt[dst[e]], 1);
}
__global__ __launch_bounds__(1024) void scan1_k(const int* __restrict__ cnt, int* __restrict__ part,
                                                int* __restrict__ bsum, int n) {
    __shared__ int buf[1024];
    int tid = threadIdx.x, gid = blockIdx.x * 1024 + tid;
    int x = (gid < n) ? cnt[gid] : 0;
    buf[tid] = x; __syncthreads();
    for (int off = 1; off < 1024; off <<= 1) {
        int y = (tid >= off) ? buf[tid - off] : 0;
        __syncthreads();
        buf[tid] += y;
        __syncthreads();
    }
    if (gid < n) part[gid] = buf[tid];
    if (tid == 1023) bsum[blockIdx.x] = buf[1023];
}
__global__ void scan2_k(int* __restrict__ bsum, int nb) {
    int tid = threadIdx.x;
    int x = (tid < nb) ? bsum[tid] : 0;
    for (int off = 1; off < 64; off <<= 1) {
        int y = __shfl_up(x, off);
        if (tid >= off) x += y;
    }
    if (tid < nb) bsum[tid] = x;
}
__global__ void scan3_k(const int* __restrict__ part, const int* __restrict__ bsum,
                        int* __restrict__ rowptr, int n) {
    int gid = blockIdx.x * 256 + threadIdx.x;
    if (gid < n) {
        int b = gid >> 10;
        int add = (b > 0) ? bsum[b - 1] : 0;
        rowptr[gid + 1] = part[gid] + add;
    }
    if (gid == 0) rowptr[0] = 0;
}
__global__ void copy_k(const int* __restrict__ a, int* __restrict__ b, int n) {
    int i = blockIdx.x * 256 + threadIdx.x;
    if (i < n) b[i] = a[i];
}
__global__ void scatter_k(const int* __restrict__ dst, int* __restrict__ cur,
                          int* __restrict__ eidx, int E) {
    int e = blockIdx.x * 256 + threadIdx.x;
    if (e < E) { int p = atomicAdd(&cur[dst[e]], 1); eidx[p] = e; }
}

// ---------- skip-mix + layernorm ----------
__global__ __launch_bounds__(256) void mix_ln(
    float* __restrict__ h, const float* __restrict__ trans, const float* __restrict__ skipP,
    const float* __restrict__ g, const float* __restrict__ b, int n)
{
    int row = blockIdx.x;
    if (row >= n) return;
    int c = threadIdx.x;
    float alpha = 1.f / (1.f + expf(-skipP[0]));
    size_t off = (size_t)row * 256 + c;
    float o = trans[off] * alpha + h[off] * (1.f - alpha);
    float s = o, ss = o * o;
    #pragma unroll
    for (int d = 1; d < 64; d <<= 1) { s += __shfl_xor(s, d); ss += __shfl_xor(ss, d); }
    __shared__ float rS[4], rSS[4];
    int w = threadIdx.x >> 6, lane = threadIdx.x & 63;
    if (lane == 0) { rS[w] = s; rSS[w] = ss; }
    __syncthreads();
    float S = rS[0] + rS[1] + rS[2] + rS[3];
    float SS = rSS[0] + rSS[1] + rSS[2] + rSS[3];
    float mean = S * (1.f / 256.f);
    float var = fmaxf(SS * (1.f / 256.f) - mean * mean, 0.f);
    float rs = rsqrtf(var + 1e-5f);
    h[off] = (o - mean) * rs * g[c] + b[c];
}

__global__ void gmax_enc(const float* __restrict__ h, const int* __restrict__ grp,
                         unsigned* __restrict__ gi, int n, int colBase) {
    int row = blockIdx.x, c = threadIdx.x;
    if (row < n) atomicMax(&gi[grp[row] * 768 + colBase + c], encf(h[(size_t)row * 256 + c]));
}

__global__ __launch_bounds__(1024) void final_k(const unsigned* __restrict__ gi,
                                                const float* __restrict__ out_w,
                                                const float* __restrict__ out_b,
                                                const float* __restrict__ y,
                                                float* __restrict__ out) {
    int w = threadIdx.x >> 6, lane = threadIdx.x & 63;
    float s = 0.f;
    for (int c = lane; c < 768; c += 64) s += decf(gi[w * 768 + c]) * out_w[c];
    #pragma unroll
    for (int d = 1; d < 64; d <<= 1) s += __shfl_xor(s, d);
    __shared__ float lloss[16];
    if (lane == 0) {
        float z = s + out_b[0];
        out[1 + w] = 1.f / (1.f + expf(-z));
        lloss[w] = fmaxf(z, 0.f) - z * y[w] + log1pf(expf(-fabsf(z)));
    }
    __syncthreads();
    if (threadIdx.x == 0) {
        float L = 0.f;
        for (int g2 = 0; g2 < 16; ++g2) L += lloss[g2];
        out[0] = L * (1.f / 16.f);
    }
}

extern "C" void kernel_launch(void* const* d_in, const int* in_sizes, int n_in,
                              void* d_out, int out_size, void* d_ws, size_t ws_size,
                              hipStream_t stream) {
    const int* word_id   = (const int*)d_in[0];
    const int* topic_id  = (const int*)d_in[1];
    const int* g_word    = (const int*)d_in[2];
    const int* g_topic   = (const int*)d_in[3];
    const int* g_doc     = (const int*)d_in[4];
    const int* src_ww = (const int*)d_in[5];  const int* dst_ww = (const int*)d_in[6];  const int* time_ww = (const int*)d_in[7];
    const int* src_wd = (const int*)d_in[8];  const int* dst_wd = (const int*)d_in[9];  const int* time_wd = (const int*)d_in[10];
    const int* src_wt = (const int*)d_in[11]; const int* dst_wt = (const int*)d_in[12]; const int* time_wt = (const int*)d_in[13];
    const int* src_td = (const int*)d_in[14]; const int* dst_td = (const int*)d_in[15]; const int* time_td = (const int*)d_in[16];
    const int* src_tt = (const int*)d_in[17]; const int* dst_tt = (const int*)d_in[18];
    const float* y_data      = (const float*)d_in[19];
    const float* word_embeds = (const float*)d_in[20];
    const float* topic_embeds= (const float*)d_in[21];
    const float* doc_gen     = (const float*)d_in[22];
    const float* adapt_w     = (const float*)d_in[23];
    const float* adapt_b     = (const float*)d_in[24];
    const float* time_tab    = (const float*)d_in[25];
    const float* time_w      = (const float*)d_in[26];
    const float* time_b      = (const float*)d_in[27];
    const float* kW = (const float*)d_in[28];
    const float* qW = (const float*)d_in[29];
    const float* vW = (const float*)d_in[30];
    const float* aW = (const float*)d_in[31];
    const float* kB = (const float*)d_in[32];
    const float* qB = (const float*)d_in[33];
    const float* vB = (const float*)d_in[34];
    const float* aB = (const float*)d_in[35];
    const float* skip = (const float*)d_in[36];
    const float* ln_g = (const float*)d_in[37];
    const float* ln_b = (const float*)d_in[38];
    const float* pri  = (const float*)d_in[39];
    const float* attR = (const float*)d_in[40];
    const float* msgR = (const float*)d_in[41];
    const float* out_w = (const float*)d_in[42];
    const float* out_b = (const float*)d_in[43];

    const int NW = in_sizes[0], NT = in_sizes[1], ND = in_sizes[4];
    const int E_ww = in_sizes[5], E_wd = in_sizes[8], E_wt = in_sizes[11],
              E_td = in_sizes[14], E_tt = in_sizes[17];
    const int nN[3] = {NW, NT, ND};
    const float invNin[3] = {1.f / 3.f, 1.f / 3.f, 1.f / 2.f};
    int Emax = E_ww;
    if (E_wd > Emax) Emax = E_wd; if (E_wt > Emax) Emax = E_wt;
    if (E_td > Emax) Emax = E_td; if (E_tt > Emax) Emax = E_tt;

    // ---- workspace carve-up ----
    float* base = (float*)d_ws;
    size_t off = 0;
    auto take = [&](size_t nElems) { float* p = base + off; off += (nElems + 63) & ~(size_t)63; return p; };
    float* hP[3]; float* kP[3]; float* qP[3]; float* vP[3]; float* tP[3];
    for (int i = 0; i < 3; ++i) hP[i] = take((size_t)nN[i] * 256);
    for (int i = 0; i < 3; ++i) kP[i] = take((size_t)nN[i] * 256);
    for (int i = 0; i < 3; ++i) qP[i] = take((size_t)nN[i] * 256);
    for (int i = 0; i < 3; ++i) vP[i] = take((size_t)nN[i] * 256);
    for (int i = 0; i < 3; ++i) tP[i] = take((size_t)nN[i] * 256);
    // union region: katt(bf16) | vmsg(bf16) during rels; trans(f32) after rels
    float* uni = take((size_t)NW * 256);
    unsigned short* katt = (unsigned short*)uni;
    unsigned short* vmsg = (unsigned short*)(uni + (size_t)NW * 128);
    float* trans = uni;
    float* alog = take((size_t)Emax * 8);
    float* den  = take((size_t)NW * 8);
    unsigned* mmax = (unsigned*)take((size_t)NW * 8);
    float* te7  = take(7 * 32);
    unsigned* gi = (unsigned*)take(16 * 768);
    int* cnt  = (int*)take(NW);
    int* part = (int*)take(NW);
    int* bsum = (int*)take(64);
    (void)ws_size; (void)n_in; (void)out_size;

    struct Rel { int e, s, d; const int* src; const int* dst; const int* tim; int E; };
    const Rel rels[8] = {
        {0, 0, 1, src_wt, dst_wt, time_wt, E_wt},
        {1, 0, 2, src_wd, dst_wd, time_wd, E_wd},
        {2, 1, 2, src_td, dst_td, time_td, E_td},
        {3, 1, 1, src_tt, dst_tt, nullptr, E_tt},
        {4, 0, 0, src_ww, dst_ww, time_ww, E_ww},
        {5, 1, 0, dst_wt, src_wt, time_wt, E_wt},
        {6, 2, 1, dst_td, src_td, time_td, E_td},
        {7, 2, 0, dst_wd, src_wd, time_wd, E_wd},
    };

    int* csr_rowptr[8]; int* csr_eidx[8];
    for (int r = 0; r < 8; ++r) {
        csr_rowptr[r] = (int*)take(nN[rels[r].d] + 1);
        csr_eidx[r]   = (int*)take(rels[r].E);
    }

    // ---- temporal table ----
    te_kernel<<<1, 256, 0, stream>>>(time_tab, time_w, time_b, te7);

    // ---- CSR build (graph is static across layers) ----
    for (int r = 0; r < 8; ++r) {
        const Rel& R = rels[r];
        int nD = nN[R.d];
        hipMemsetAsync(cnt, 0, (size_t)nD * sizeof(int), stream);
        count_k<<<(R.E + 255) / 256, 256, 0, stream>>>(R.dst, cnt, R.E);
        int nb = (nD + 1023) / 1024;
        scan1_k<<<nb, 1024, 0, stream>>>(cnt, part, bsum, nD);
        scan2_k<<<1, 64, 0, stream>>>(bsum, nb);
        scan3_k<<<(nD + 255) / 256, 256, 0, stream>>>(part, bsum, csr_rowptr[r], nD);
        copy_k<<<(nD + 255) / 256, 256, 0, stream>>>(csr_rowptr[r], cnt, nD);
        scatter_k<<<(R.E + 255) / 256, 256, 0, stream>>>(R.dst, cnt, csr_eidx[r], R.E);
    }

    // ---- init node features ----
    {
        dim3 g((NW + 63) / 64, 4);
        gemm_n256<<<g, 256, 0, stream>>>(word_embeds, word_id, adapt_w, adapt_b, hP[0], NW, 1.f);
    }
    gather_rows<<<NT, 256, 0, stream>>>(topic_embeds, topic_id, hP[1], NT);
    bcast_row<<<ND, 256, 0, stream>>>(doc_gen, hP[2], ND);

    // ---- layers ----
    for (int li = 0; li < LNUM; ++li) {
        for (int i = 0; i < 3; ++i)
            hipMemsetAsync(tP[i], 0, (size_t)nN[i] * 256 * sizeof(float), stream);

        for (int i = 0; i < 3; ++i) {
            dim3 g((nN[i] + 63) / 64, 4);
            size_t wOff = ((size_t)li * 3 + i) * 65536;
            size_t bOff = ((size_t)li * 3 + i) * 256;
            gemm_n256<<<g, 256, 0, stream>>>(hP[i], nullptr, kW + wOff, kB + bOff, kP[i], nN[i], 1.f);
            gemm_n256<<<g, 256, 0, stream>>>(hP[i], nullptr, qW + wOff, qB + bOff, qP[i], nN[i], 1.f);
            gemm_n256<<<g, 256, 0, stream>>>(hP[i], nullptr, vW + wOff, vB + bOff, vP[i], nN[i], 1.f);
        }

        for (int r = 0; r < 8; ++r) {
            const Rel& R = rels[r];
            int nS = nN[R.s], nD = nN[R.d];
            size_t rOff = ((size_t)li * 8 + R.e) * 8192;
            size_t pOff = ((size_t)li * 8 + R.e) * 8;
            dim3 gb((nS + 63) / 64, 8);
            bd_gemm<<<gb, 256, 0, stream>>>(kP[R.s], attR + rOff, katt, nS);
            bd_gemm<<<gb, 256, 0, stream>>>(vP[R.s], msgR + rOff, vmsg, nS);
            hipMemsetAsync(mmax, 0, (size_t)nD * 8 * sizeof(unsigned), stream);
            hipMemsetAsync(den, 0, (size_t)nD * 8 * sizeof(float), stream);
            int egrid = (R.E * 8 + 255) / 256;
            ek1b<<<egrid, 256, 0, stream>>>(qP[R.d], katt, R.src, R.dst, pri + pOff, alog, mmax, R.E);
            ek2_expsum<<<egrid, 256, 0, stream>>>(R.dst, alog, mmax, den, R.E);
            ek3_csr<<<(nD + 3) / 4, 256, 0, stream>>>(vmsg, R.src, R.tim, csr_rowptr[r], csr_eidx[r],
                                                      te7, alog, den, tP[R.d], nD);
        }

        for (int i = 0; i < 3; ++i) {
            dim3 g((nN[i] + 63) / 64, 4);
            size_t wOff = ((size_t)li * 3 + i) * 65536;
            size_t bOff = ((size_t)li * 3 + i) * 256;
            gemm_n256<<<g, 256, 0, stream>>>(tP[i], nullptr, aW + wOff, aB + bOff, trans, nN[i], invNin[i]);
            mix_ln<<<nN[i], 256, 0, stream>>>(hP[i], trans, skip + ((size_t)li * 3 + i),
                                              ln_g + bOff, ln_b + bOff, nN[i]);
        }
    }

    // ---- readout ----
    hipMemsetAsync(gi, 0, 16 * 768 * sizeof(unsigned), stream);
    gmax_enc<<<ND, 256, 0, stream>>>(hP[2], g_doc, gi, ND, 0);
    gmax_enc<<<NW, 256, 0, stream>>>(hP[0], g_word, gi, NW, 256);
    gmax_enc<<<NT, 256, 0, stream>>>(hP[1], g_topic, gi, NT, 512);
    final_k<<<1, 1024, 0, stream>>>(gi, out_w, out_b, y_data, (float*)d_out);
}

// Round 3
// 1532.332 us; speedup vs baseline: 5.5945x; 1.5944x over previous
//
#include <hip/hip_runtime.h>
#include <hip/hip_bf16.h>
#include <math.h>

#define H 8
#define DK 32
#define NHID 256
#define LNUM 2
#define GNUM 16

typedef float f32x4 __attribute__((ext_vector_type(4)));
typedef short bf16x8 __attribute__((ext_vector_type(8)));
typedef unsigned short u16x8 __attribute__((ext_vector_type(8)));

__device__ __forceinline__ float bfd(unsigned short u) {
    return __uint_as_float(((unsigned)u) << 16);
}
__device__ __forceinline__ unsigned short f2bf(float x) {
    __hip_bfloat16 b = __float2bfloat16(x);
    return *reinterpret_cast<unsigned short*>(&b);
}
__device__ __forceinline__ int lbound(const int* __restrict__ a, int n, int v) {
    int lo = 0, hi = n;
    while (lo < hi) { int mid = (lo + hi) >> 1; if (a[mid] < v) lo = mid + 1; else hi = mid; }
    return lo;
}

// ---------- temporal encoding table ----------
__global__ void te_kernel(const float* __restrict__ time_tab, const float* __restrict__ time_w,
                          const float* __restrict__ time_b, float* __restrict__ te7) {
    int t = threadIdx.x >> 5, j = threadIdx.x & 31;
    if (t < 7) {
        float s = time_b[j];
        #pragma unroll
        for (int i = 0; i < 32; ++i) s += time_tab[t * 32 + i] * time_w[i * 32 + j];
        te7[t * 32 + j] = s;
    }
}

__global__ void gather_rows(const float* __restrict__ emb, const int* __restrict__ idx,
                            float* __restrict__ out, int n) {
    int row = blockIdx.x, c = threadIdx.x;
    if (row < n) out[(size_t)row * 256 + c] = emb[(size_t)idx[row] * 256 + c];
}

__global__ void bcast_row(const float* __restrict__ src, float* __restrict__ out, int n) {
    int row = blockIdx.x, c = threadIdx.x;
    if (row < n) out[(size_t)row * 256 + c] = src[c];
}

// ---------- weight transpose+bf16: WT[z][col][k] = W_z[k][col]; z: 0=adapt,1-6 kW,7-12 qW,13-18 vW,19-24 aW
__global__ __launch_bounds__(256) void wtr_kernel(
    const float* __restrict__ adaptW, const float* __restrict__ kW, const float* __restrict__ qW,
    const float* __restrict__ vW, const float* __restrict__ aW, unsigned short* __restrict__ WT) {
    int z = blockIdx.z;
    const float* src;
    if (z == 0) src = adaptW;
    else if (z < 7)  src = kW + (size_t)(z - 1) * 65536;
    else if (z < 13) src = qW + (size_t)(z - 7) * 65536;
    else if (z < 19) src = vW + (size_t)(z - 13) * 65536;
    else             src = aW + (size_t)(z - 19) * 65536;
    unsigned short* dst = WT + (size_t)z * 65536;
    __shared__ float tile[32][33];
    int tx = threadIdx.x & 31, ty = threadIdx.x >> 5;
    int kb = blockIdx.x * 32, cb = blockIdx.y * 32;
    #pragma unroll
    for (int i = 0; i < 4; ++i)
        tile[ty + i * 8][tx] = src[(size_t)(kb + ty + i * 8) * 256 + cb + tx];
    __syncthreads();
    #pragma unroll
    for (int i = 0; i < 4; ++i)
        dst[(size_t)(cb + ty + i * 8) * 256 + kb + tx] = f2bf(tile[tx][ty + i * 8]);
}

// ---------- MFMA GEMM: out[n,256] = (A[gather][256]*inScale) @ W + bias ----------
// 64x64 tile, BK=64, bf16 LDS with 16B-granule XOR swizzle. z selects weight/bias/out (fused kqv).
#define AIDX(row, kb) (((row) << 6) + ((((kb) ^ (((row) & 7) << 4))) >> 1))
__global__ __launch_bounds__(256) void gemm_mfma(
    const float* __restrict__ A, const int* __restrict__ gidx,
    const unsigned short* __restrict__ WT, int wStride,
    const float* __restrict__ b0, const float* __restrict__ b1, const float* __restrict__ b2,
    void* __restrict__ o0, void* __restrict__ o1, void* __restrict__ o2,
    int n, float inScale, int outBf16)
{
    __shared__ unsigned short As[64 * 64];
    __shared__ unsigned short Bs[64 * 64];
    const int z = blockIdx.z;
    const unsigned short* W = WT + (size_t)z * wStride;
    const float* bias = (z == 0) ? b0 : ((z == 1) ? b1 : b2);
    void* outp = (z == 0) ? o0 : ((z == 1) ? o1 : o2);
    const int tid = threadIdx.x;
    const int rowBase = blockIdx.x * 64, colBase = blockIdx.y * 64;
    const int lr = tid >> 2, lq = tid & 3;
    const int arow = rowBase + lr;
    const bool aval = arow < n;
    const int ar = aval ? (gidx ? gidx[arow] : arow) : 0;
    const float* Ap = A + (size_t)ar * 256 + lq * 16;
    const unsigned short* Bp = W + (size_t)(colBase + lr) * 256 + lq * 16;
    const int lane = tid & 63, wv = tid >> 6;
    const int fr = lane & 15, fg = lane >> 4;
    const int wrow = (wv & 1) * 32, wcol = (wv >> 1) * 32;
    f32x4 acc[2][2];
    #pragma unroll
    for (int m = 0; m < 2; ++m)
        #pragma unroll
        for (int nn = 0; nn < 2; ++nn) acc[m][nn] = 0.f;

    for (int ks = 0; ks < 4; ++ks) {
        float4 a0 = make_float4(0,0,0,0), a1 = a0, a2 = a0, a3 = a0;
        if (aval) {
            a0 = *reinterpret_cast<const float4*>(Ap + ks * 64 + 0);
            a1 = *reinterpret_cast<const float4*>(Ap + ks * 64 + 4);
            a2 = *reinterpret_cast<const float4*>(Ap + ks * 64 + 8);
            a3 = *reinterpret_cast<const float4*>(Ap + ks * 64 + 12);
        }
        u16x8 bv0 = *reinterpret_cast<const u16x8*>(Bp + ks * 64);
        u16x8 bv1 = *reinterpret_cast<const u16x8*>(Bp + ks * 64 + 8);
        u16x8 pa0, pa1;
        pa0[0] = f2bf(a0.x * inScale); pa0[1] = f2bf(a0.y * inScale);
        pa0[2] = f2bf(a0.z * inScale); pa0[3] = f2bf(a0.w * inScale);
        pa0[4] = f2bf(a1.x * inScale); pa0[5] = f2bf(a1.y * inScale);
        pa0[6] = f2bf(a1.z * inScale); pa0[7] = f2bf(a1.w * inScale);
        pa1[0] = f2bf(a2.x * inScale); pa1[1] = f2bf(a2.y * inScale);
        pa1[2] = f2bf(a2.z * inScale); pa1[3] = f2bf(a2.w * inScale);
        pa1[4] = f2bf(a3.x * inScale); pa1[5] = f2bf(a3.y * inScale);
        pa1[6] = f2bf(a3.z * inScale); pa1[7] = f2bf(a3.w * inScale);
        __syncthreads();
        *reinterpret_cast<u16x8*>(&As[AIDX(lr, lq * 32)])      = pa0;
        *reinterpret_cast<u16x8*>(&As[AIDX(lr, lq * 32 + 16)]) = pa1;
        *reinterpret_cast<u16x8*>(&Bs[AIDX(lr, lq * 32)])      = bv0;
        *reinterpret_cast<u16x8*>(&Bs[AIDX(lr, lq * 32 + 16)]) = bv1;
        __syncthreads();
        #pragma unroll
        for (int kk = 0; kk < 2; ++kk) {
            bf16x8 af0 = *reinterpret_cast<bf16x8*>(&As[AIDX(wrow + fr,      kk * 64 + fg * 16)]);
            bf16x8 af1 = *reinterpret_cast<bf16x8*>(&As[AIDX(wrow + 16 + fr, kk * 64 + fg * 16)]);
            bf16x8 bf0 = *reinterpret_cast<bf16x8*>(&Bs[AIDX(wcol + fr,      kk * 64 + fg * 16)]);
            bf16x8 bf1 = *reinterpret_cast<bf16x8*>(&Bs[AIDX(wcol + 16 + fr, kk * 64 + fg * 16)]);
            acc[0][0] = __builtin_amdgcn_mfma_f32_16x16x32_bf16(af0, bf0, acc[0][0], 0, 0, 0);
            acc[0][1] = __builtin_amdgcn_mfma_f32_16x16x32_bf16(af0, bf1, acc[0][1], 0, 0, 0);
            acc[1][0] = __builtin_amdgcn_mfma_f32_16x16x32_bf16(af1, bf0, acc[1][0], 0, 0, 0);
            acc[1][1] = __builtin_amdgcn_mfma_f32_16x16x32_bf16(af1, bf1, acc[1][1], 0, 0, 0);
        }
    }
    #pragma unroll
    for (int m = 0; m < 2; ++m) {
        #pragma unroll
        for (int r = 0; r < 4; ++r) {
            int gr = rowBase + wrow + m * 16 + fg * 4 + r;
            if (gr >= n) continue;
            #pragma unroll
            for (int nn = 0; nn < 2; ++nn) {
                int gc = colBase + wcol + nn * 16 + fr;
                float v = acc[m][nn][r] + bias[gc];
                if (outBf16) ((unsigned short*)outp)[(size_t)gr * 256 + gc] = f2bf(v);
                else         ((float*)outp)[(size_t)gr * 256 + gc] = v;
            }
        }
    }
}

// ---------- block-diagonal per-head transform (bf16 in/out); z: 0 -> (k,attR,katt), 1 -> (v,msgR,vmsg)
__global__ __launch_bounds__(256) void bd_gemm(
    const unsigned short* __restrict__ in0, const unsigned short* __restrict__ in1,
    const float* __restrict__ R0, const float* __restrict__ R1,
    unsigned short* __restrict__ out0, unsigned short* __restrict__ out1, int n)
{
    const unsigned short* in = blockIdx.z ? in1 : in0;
    const float* R = blockIdx.z ? R1 : R0;
    unsigned short* out = blockIdx.z ? out1 : out0;
    __shared__ float As[64 * 33];
    __shared__ float Rs[32 * 33];
    const int tid = threadIdx.x;
    const int head = blockIdx.y;
    const int rowBase = blockIdx.x * 64;
    {
        int row = tid >> 2, q = tid & 3;
        int r = rowBase + row;
        u16x8 v = {};
        if (r < n) v = *reinterpret_cast<const u16x8*>(in + (size_t)r * 256 + head * 32 + q * 8);
        float* ap = &As[row * 33 + q * 8];
        #pragma unroll
        for (int j = 0; j < 8; ++j) ap[j] = (r < n) ? bfd(v[j]) : 0.f;
    }
    {
        int k = tid >> 3, l0 = (tid & 7) * 4;
        float4 rv = *reinterpret_cast<const float4*>(R + head * 1024 + k * 32 + l0);
        float* rp = &Rs[k * 33 + l0];
        rp[0] = rv.x; rp[1] = rv.y; rp[2] = rv.z; rp[3] = rv.w;
    }
    __syncthreads();
    const int wv = tid >> 6, lane = tid & 63;
    float acc[8] = {0.f, 0.f, 0.f, 0.f, 0.f, 0.f, 0.f, 0.f};
    #pragma unroll
    for (int k = 0; k < 32; ++k) {
        float a = As[lane * 33 + k];
        const float* rp = &Rs[k * 33 + wv * 8];
        #pragma unroll
        for (int j = 0; j < 8; ++j) acc[j] += a * rp[j];
    }
    int r = rowBase + lane;
    if (r < n) {
        ushort4 o0, o1;
        o0.x = f2bf(acc[0]); o0.y = f2bf(acc[1]); o0.z = f2bf(acc[2]); o0.w = f2bf(acc[3]);
        o1.x = f2bf(acc[4]); o1.y = f2bf(acc[5]); o1.z = f2bf(acc[6]); o1.w = f2bf(acc[7]);
        ushort4* po = reinterpret_cast<ushort4*>(out + (size_t)r * 256 + head * 32 + wv * 8);
        po[0] = o0; po[1] = o1;
    }
}

// ---------- EK1: a = dot(q[dst][h], katt[src][h]) * pri/sqrt(DK) -> alog ----------
__global__ __launch_bounds__(256) void ek1b(
    const unsigned short* __restrict__ qbuf, const unsigned short* __restrict__ katt,
    const int* __restrict__ src, const int* __restrict__ dst,
    const float* __restrict__ pri, float* __restrict__ alog, int E)
{
    int gid = blockIdx.x * 256 + threadIdx.x;
    int e = gid >> 3, h = gid & 7;
    if (e >= E) return;
    int s = src[e], d = dst[e];
    const u16x8* q8 = reinterpret_cast<const u16x8*>(qbuf + (size_t)d * 256 + h * 32);
    const u16x8* k8 = reinterpret_cast<const u16x8*>(katt + (size_t)s * 256 + h * 32);
    float a = 0.f;
    #pragma unroll
    for (int j = 0; j < 4; ++j) {
        u16x8 qv = q8[j], kv = k8[j];
        #pragma unroll
        for (int m = 0; m < 8; ++m) a += bfd(qv[m]) * bfd(kv[m]);
    }
    a *= pri[h] * 0.17677669529663687f;
    alog[(size_t)e * 8 + h] = a;
}

// ---------- EK3 (fused max/exp/den/agg, CSR, no atomics) ----------
__global__ __launch_bounds__(256) void ek3_fused(
    const unsigned short* __restrict__ vmsg, const int* __restrict__ src, const int* __restrict__ tim,
    const int* __restrict__ rowptr, const int* __restrict__ eidx,
    const float* __restrict__ te7, const float* __restrict__ alog,
    float* __restrict__ tacc, int nD)
{
    __shared__ float sTe[224];
    if (threadIdx.x < 224) sTe[threadIdx.x] = te7[threadIdx.x];
    __syncthreads();
    int wv = threadIdx.x >> 6, lane = threadIdx.x & 63;
    int d = blockIdx.x * 4 + wv;
    if (d >= nD) return;
    int beg = rowptr[d], end = rowptr[d + 1];
    if (beg == end) return;
    int c = lane * 4, h = lane >> 3;
    float m = -INFINITY;
    for (int p = beg; p < end; ++p) m = fmaxf(m, alog[(size_t)eidx[p] * 8 + h]);
    float den = 0.f, a0 = 0.f, a1 = 0.f, a2 = 0.f, a3 = 0.f;
    for (int p = beg; p < end; ++p) {
        int e = eidx[p], s = src[e];
        float ex = __expf(alog[(size_t)e * 8 + h] - m);
        den += ex;
        ushort4 v = *reinterpret_cast<const ushort4*>(vmsg + (size_t)s * 256 + c);
        float vx = bfd(v.x), vy = bfd(v.y), vz = bfd(v.z), vw = bfd(v.w);
        if (tim) {
            const float* tp = &sTe[tim[e] * 32 + (c & 31)];
            vx += tp[0]; vy += tp[1]; vz += tp[2]; vw += tp[3];
        }
        a0 += ex * vx; a1 += ex * vy; a2 += ex * vz; a3 += ex * vw;
    }
    float invden = 1.f / fmaxf(den, 1e-9f);
    float4* tp4 = reinterpret_cast<float4*>(tacc + (size_t)d * 256 + c);
    float4 o = *tp4;
    o.x += fmaxf(a0 * invden, 0.f); o.y += fmaxf(a1 * invden, 0.f);
    o.z += fmaxf(a2 * invden, 0.f); o.w += fmaxf(a3 * invden, 0.f);
    *tp4 = o;
}

// ---------- CSR build ----------
__global__ void count_k(const int* __restrict__ dst, int* __restrict__ cnt, int E) {
    int e = blockIdx.x * 256 + threadIdx.x;
    if (e < E) atomicAdd(&cnt[dst[e]], 1);
}
__global__ __launch_bounds__(1024) void scan_full(const int* __restrict__ cnt,
                                                  int* __restrict__ rowptr, int* __restrict__ cur, int n) {
    __shared__ int buf[1024];
    int tid = threadIdx.x;
    int carry = 0;
    int nch = (n + 1023) >> 10;
    for (int ch = 0; ch < nch; ++ch) {
        int gid = (ch << 10) + tid;
        int x = (gid < n) ? cnt[gid] : 0;
        buf[tid] = x;
        __syncthreads();
        for (int off2 = 1; off2 < 1024; off2 <<= 1) {
            int y = (tid >= off2) ? buf[tid - off2] : 0;
            __syncthreads();
            buf[tid] += y;
            __syncthreads();
        }
        int inc = buf[tid] + carry;
        if (gid < n) { rowptr[gid + 1] = inc; cur[gid] = inc - x; }
        carry += buf[1023];
        __syncthreads();
    }
    if (tid == 0) rowptr[0] = 0;
}
__global__ void scatter_k(const int* __restrict__ dst, int* __restrict__ cur,
                          int* __restrict__ eidx, int E) {
    int e = blockIdx.x * 256 + threadIdx.x;
    if (e < E) { int p = atomicAdd(&cur[dst[e]], 1); eidx[p] = e; }
}

// ---------- skip-mix + layernorm ----------
__global__ __launch_bounds__(256) void mix_ln(
    float* __restrict__ h, const float* __restrict__ trans, const float* __restrict__ skipP,
    const float* __restrict__ g, const float* __restrict__ b, int n)
{
    int row = blockIdx.x;
    if (row >= n) return;
    int c = threadIdx.x;
    float alpha = 1.f / (1.f + expf(-skipP[0]));
    size_t off = (size_t)row * 256 + c;
    float o = trans[off] * alpha + h[off] * (1.f - alpha);
    float s = o, ss = o * o;
    #pragma unroll
    for (int d = 1; d < 64; d <<= 1) { s += __shfl_xor(s, d); ss += __shfl_xor(ss, d); }
    __shared__ float rS[4], rSS[4];
    int w = threadIdx.x >> 6, lane = threadIdx.x & 63;
    if (lane == 0) { rS[w] = s; rSS[w] = ss; }
    __syncthreads();
    float S = rS[0] + rS[1] + rS[2] + rS[3];
    float SS = rSS[0] + rSS[1] + rSS[2] + rSS[3];
    float mean = S * (1.f / 256.f);
    float var = fmaxf(SS * (1.f / 256.f) - mean * mean, 0.f);
    float rs = rsqrtf(var + 1e-5f);
    h[off] = (o - mean) * rs * g[c] + b[c];
}

// ---------- segmented group max (sorted groups, no atomics) ----------
__global__ __launch_bounds__(256) void gmax_seg(const float* __restrict__ h, const int* __restrict__ grp,
                                                float* __restrict__ gi, int n, int colBase) {
    int g = blockIdx.x, cb = blockIdx.y;
    int lo = lbound(grp, n, g), hi = lbound(grp, n, g + 1);
    int tid = threadIdx.x;
    int col = cb * 64 + (tid & 63), ro = tid >> 6;
    float m = -INFINITY;
    for (int r = lo + ro; r < hi; r += 4) m = fmaxf(m, h[(size_t)r * 256 + col]);
    __shared__ float s[256];
    s[tid] = m;
    __syncthreads();
    if (tid < 64) {
        float m2 = fmaxf(fmaxf(s[tid], s[tid + 64]), fmaxf(s[tid + 128], s[tid + 192]));
        gi[g * 768 + colBase + cb * 64 + tid] = m2;
    }
}

// ---------- final: logits, loss, sigmoid ----------
__global__ __launch_bounds__(1024) void final_k(const float* __restrict__ gi,
                                                const float* __restrict__ out_w,
                                                const float* __restrict__ out_b,
                                                const float* __restrict__ y,
                                                float* __restrict__ out) {
    int w = threadIdx.x >> 6, lane = threadIdx.x & 63;
    float s = 0.f;
    for (int c = lane; c < 768; c += 64) s += gi[w * 768 + c] * out_w[c];
    #pragma unroll
    for (int d = 1; d < 64; d <<= 1) s += __shfl_xor(s, d);
    __shared__ float lloss[16];
    if (lane == 0) {
        float z = s + out_b[0];
        out[1 + w] = 1.f / (1.f + expf(-z));
        lloss[w] = fmaxf(z, 0.f) - z * y[w] + log1pf(expf(-fabsf(z)));
    }
    __syncthreads();
    if (threadIdx.x == 0) {
        float L = 0.f;
        for (int g2 = 0; g2 < 16; ++g2) L += lloss[g2];
        out[0] = L * (1.f / 16.f);
    }
}

extern "C" void kernel_launch(void* const* d_in, const int* in_sizes, int n_in,
                              void* d_out, int out_size, void* d_ws, size_t ws_size,
                              hipStream_t stream) {
    const int* word_id   = (const int*)d_in[0];
    const int* topic_id  = (const int*)d_in[1];
    const int* g_word    = (const int*)d_in[2];
    const int* g_topic   = (const int*)d_in[3];
    const int* g_doc     = (const int*)d_in[4];
    const int* src_ww = (const int*)d_in[5];  const int* dst_ww = (const int*)d_in[6];  const int* time_ww = (const int*)d_in[7];
    const int* src_wd = (const int*)d_in[8];  const int* dst_wd = (const int*)d_in[9];  const int* time_wd = (const int*)d_in[10];
    const int* src_wt = (const int*)d_in[11]; const int* dst_wt = (const int*)d_in[12]; const int* time_wt = (const int*)d_in[13];
    const int* src_td = (const int*)d_in[14]; const int* dst_td = (const int*)d_in[15]; const int* time_td = (const int*)d_in[16];
    const int* src_tt = (const int*)d_in[17]; const int* dst_tt = (const int*)d_in[18];
    const float* y_data      = (const float*)d_in[19];
    const float* word_embeds = (const float*)d_in[20];
    const float* topic_embeds= (const float*)d_in[21];
    const float* doc_gen     = (const float*)d_in[22];
    const float* adapt_w     = (const float*)d_in[23];
    const float* adapt_b     = (const float*)d_in[24];
    const float* time_tab    = (const float*)d_in[25];
    const float* time_w      = (const float*)d_in[26];
    const float* time_b      = (const float*)d_in[27];
    const float* kW = (const float*)d_in[28];
    const float* qW = (const float*)d_in[29];
    const float* vW = (const float*)d_in[30];
    const float* aW = (const float*)d_in[31];
    const float* kB = (const float*)d_in[32];
    const float* qB = (const float*)d_in[33];
    const float* vB = (const float*)d_in[34];
    const float* aB = (const float*)d_in[35];
    const float* skip = (const float*)d_in[36];
    const float* ln_g = (const float*)d_in[37];
    const float* ln_b = (const float*)d_in[38];
    const float* pri  = (const float*)d_in[39];
    const float* attR = (const float*)d_in[40];
    const float* msgR = (const float*)d_in[41];
    const float* out_w = (const float*)d_in[42];
    const float* out_b = (const float*)d_in[43];

    const int NW = in_sizes[0], NT = in_sizes[1], ND = in_sizes[4];
    const int E_ww = in_sizes[5], E_wd = in_sizes[8], E_wt = in_sizes[11],
              E_td = in_sizes[14], E_tt = in_sizes[17];
    const int nN[3] = {NW, NT, ND};
    const float invNin[3] = {1.f / 3.f, 1.f / 3.f, 1.f / 2.f};
    int Emax = E_ww;
    if (E_wd > Emax) Emax = E_wd; if (E_wt > Emax) Emax = E_wt;
    if (E_td > Emax) Emax = E_td; if (E_tt > Emax) Emax = E_tt;

    // ---- workspace carve-up (units of float) ----
    float* base = (float*)d_ws;
    size_t off = 0;
    auto take = [&](size_t nElems) { float* p = base + off; off += (nElems + 63) & ~(size_t)63; return p; };
    float* hP[3]; float* tP[3];
    unsigned short* kP[3]; unsigned short* qP[3]; unsigned short* vP[3];
    for (int i = 0; i < 3; ++i) hP[i] = take((size_t)nN[i] * 256);
    for (int i = 0; i < 3; ++i) tP[i] = take((size_t)nN[i] * 256);
    for (int i = 0; i < 3; ++i) kP[i] = (unsigned short*)take((size_t)nN[i] * 128);
    for (int i = 0; i < 3; ++i) qP[i] = (unsigned short*)take((size_t)nN[i] * 128);
    for (int i = 0; i < 3; ++i) vP[i] = (unsigned short*)take((size_t)nN[i] * 128);
    // union: katt|vmsg (bf16) during rels; trans (f32) after
    float* uni = take((size_t)NW * 256);
    unsigned short* katt = (unsigned short*)uni;
    unsigned short* vmsg = (unsigned short*)(uni + (size_t)NW * 128);
    float* trans = uni;
    unsigned short* WT = (unsigned short*)take((size_t)25 * 32768);  // 25 matrices bf16
    float* alog = take((size_t)Emax * 8);
    float* te7  = take(7 * 32);
    float* gi   = take(16 * 768);
    int* cnt = (int*)take(NW);
    int* cur = (int*)take(NW);
    (void)ws_size; (void)n_in; (void)out_size;

    struct Rel { int e, s, d; const int* src; const int* dst; const int* tim; int E; };
    const Rel rels[8] = {
        {0, 0, 1, src_wt, dst_wt, time_wt, E_wt},
        {1, 0, 2, src_wd, dst_wd, time_wd, E_wd},
        {2, 1, 2, src_td, dst_td, time_td, E_td},
        {3, 1, 1, src_tt, dst_tt, nullptr, E_tt},
        {4, 0, 0, src_ww, dst_ww, time_ww, E_ww},
        {5, 1, 0, dst_wt, src_wt, time_wt, E_wt},
        {6, 2, 1, dst_td, src_td, time_td, E_td},
        {7, 2, 0, dst_wd, src_wd, time_wd, E_wd},
    };
    int* csr_rowptr[8]; int* csr_eidx[8];
    for (int r = 0; r < 8; ++r) {
        csr_rowptr[r] = (int*)take(nN[rels[r].d] + 1);
        csr_eidx[r]   = (int*)take(rels[r].E);
    }

    te_kernel<<<1, 256, 0, stream>>>(time_tab, time_w, time_b, te7);
    {
        dim3 g(8, 8, 25);
        wtr_kernel<<<g, 256, 0, stream>>>(adapt_w, kW, qW, vW, aW, WT);
    }

    // ---- CSR build ----
    for (int r = 0; r < 8; ++r) {
        const Rel& R = rels[r];
        int nD = nN[R.d];
        hipMemsetAsync(cnt, 0, (size_t)nD * sizeof(int), stream);
        count_k<<<(R.E + 255) / 256, 256, 0, stream>>>(R.dst, cnt, R.E);
        scan_full<<<1, 1024, 0, stream>>>(cnt, csr_rowptr[r], cur, nD);
        scatter_k<<<(R.E + 255) / 256, 256, 0, stream>>>(R.dst, cur, csr_eidx[r], R.E);
    }

    // ---- init node features ----
    {
        dim3 g((NW + 63) / 64, 4, 1);
        gemm_mfma<<<g, 256, 0, stream>>>(word_embeds, word_id, WT, 0,
                                         adapt_b, adapt_b, adapt_b,
                                         hP[0], hP[0], hP[0], NW, 1.f, 0);
    }
    gather_rows<<<NT, 256, 0, stream>>>(topic_embeds, topic_id, hP[1], NT);
    bcast_row<<<ND, 256, 0, stream>>>(doc_gen, hP[2], ND);

    // ---- layers ----
    for (int li = 0; li < LNUM; ++li) {
        for (int i = 0; i < 3; ++i)
            hipMemsetAsync(tP[i], 0, (size_t)nN[i] * 256 * sizeof(float), stream);

        for (int i = 0; i < 3; ++i) {
            int j = li * 3 + i;
            dim3 g((nN[i] + 63) / 64, 4, 3);
            gemm_mfma<<<g, 256, 0, stream>>>(hP[i], nullptr, WT + (size_t)(1 + j) * 65536, 6 * 65536,
                                             kB + (size_t)j * 256, qB + (size_t)j * 256, vB + (size_t)j * 256,
                                             kP[i], qP[i], vP[i], nN[i], 1.f, 1);
        }

        for (int r = 0; r < 8; ++r) {
            const Rel& R = rels[r];
            int nS = nN[R.s], nD = nN[R.d];
            size_t rOff = ((size_t)li * 8 + R.e) * 8192;
            size_t pOff = ((size_t)li * 8 + R.e) * 8;
            dim3 gb((nS + 63) / 64, 8, 2);
            bd_gemm<<<gb, 256, 0, stream>>>(kP[R.s], vP[R.s], attR + rOff, msgR + rOff, katt, vmsg, nS);
            int egrid = (R.E * 8 + 255) / 256;
            ek1b<<<egrid, 256, 0, stream>>>(qP[R.d], katt, R.src, R.dst, pri + pOff, alog, R.E);
            ek3_fused<<<(nD + 3) / 4, 256, 0, stream>>>(vmsg, R.src, R.tim, csr_rowptr[r], csr_eidx[r],
                                                        te7, alog, tP[R.d], nD);
        }

        for (int i = 0; i < 3; ++i) {
            int j = li * 3 + i;
            dim3 g((nN[i] + 63) / 64, 4, 1);
            gemm_mfma<<<g, 256, 0, stream>>>(tP[i], nullptr, WT + (size_t)(19 + j) * 65536, 0,
                                             aB + (size_t)j * 256, aB + (size_t)j * 256, aB + (size_t)j * 256,
                                             trans, trans, trans, nN[i], invNin[i], 0);
            mix_ln<<<nN[i], 256, 0, stream>>>(hP[i], trans, skip + (size_t)j,
                                              ln_g + (size_t)j * 256, ln_b + (size_t)j * 256, nN[i]);
        }
    }

    // ---- readout ----
    {
        dim3 gg(16, 4);
        gmax_seg<<<gg, 256, 0, stream>>>(hP[2], g_doc, gi, ND, 0);
        gmax_seg<<<gg, 256, 0, stream>>>(hP[0], g_word, gi, NW, 256);
        gmax_seg<<<gg, 256, 0, stream>>>(hP[1], g_topic, gi, NT, 512);
    }
    final_k<<<1, 1024, 0, stream>>>(gi, out_w, out_b, y_data, (float*)d_out);
}

// Round 4
// 1018.256 us; speedup vs baseline: 8.4189x; 1.5049x over previous
//
#include <hip/hip_runtime.h>
#include <hip/hip_bf16.h>
#include <math.h>

#define H 8
#define DK 32
#define NHID 256
#define LNUM 2
#define GNUM 16

typedef float f32x4 __attribute__((ext_vector_type(4)));
typedef short bf16x8 __attribute__((ext_vector_type(8)));
typedef unsigned short u16x8 __attribute__((ext_vector_type(8)));

__device__ __forceinline__ unsigned encf(float f) {
    unsigned u = __float_as_uint(f);
    return (u & 0x80000000u) ? ~u : (u | 0x80000000u);
}
__device__ __forceinline__ float decf(unsigned u) {
    return __uint_as_float((u & 0x80000000u) ? (u ^ 0x80000000u) : ~u);
}
__device__ __forceinline__ float bfd(unsigned short u) {
    return __uint_as_float(((unsigned)u) << 16);
}
__device__ __forceinline__ unsigned short f2bf(float x) {
    __hip_bfloat16 b = __float2bfloat16(x);
    return *reinterpret_cast<unsigned short*>(&b);
}

// ---------- by-value arg structs ----------
struct CsrArgs { const int* dst[8]; int relOfs[9]; int dstBase[8]; };
struct BdArgs  { const unsigned short* inK[3]; const unsigned short* inV[3];
                 const float* RA[3]; const float* RM[3]; const float* priP[3];
                 int rows[3]; int rowOfs[3]; };
struct Ek1Args { const int* src[3]; const int* dst[3]; int E[3]; int eBase[3]; int rowOfs[3]; };
struct Ek3Args { const int* src[3]; const int* tim[3]; int eBase[3]; int dstBase[3];
                 int rowOfs[3]; int nr; int nD; };
struct GmaxArgs{ const float* hp[3]; const int* grp[3]; int n[3]; int colBase[3]; };

// ---------- temporal encoding table ----------
__global__ void te_kernel(const float* __restrict__ time_tab, const float* __restrict__ time_w,
                          const float* __restrict__ time_b, float* __restrict__ te7) {
    int t = threadIdx.x >> 5, j = threadIdx.x & 31;
    if (t < 7) {
        float s = time_b[j];
        #pragma unroll
        for (int i = 0; i < 32; ++i) s += time_tab[t * 32 + i] * time_w[i * 32 + j];
        te7[t * 32 + j] = s;
    }
}

__global__ void gather_rows(const float* __restrict__ emb, const int* __restrict__ idx,
                            float* __restrict__ out, int n) {
    int row = blockIdx.x, c = threadIdx.x;
    if (row < n) out[(size_t)row * 256 + c] = emb[(size_t)idx[row] * 256 + c];
}

__global__ void bcast_row(const float* __restrict__ src, float* __restrict__ out, int n) {
    int row = blockIdx.x, c = threadIdx.x;
    if (row < n) out[(size_t)row * 256 + c] = src[c];
}

// ---------- weight transpose+bf16 ----------
__global__ __launch_bounds__(256) void wtr_kernel(
    const float* __restrict__ adaptW, const float* __restrict__ kW, const float* __restrict__ qW,
    const float* __restrict__ vW, const float* __restrict__ aW, unsigned short* __restrict__ WT) {
    int z = blockIdx.z;
    const float* src;
    if (z == 0) src = adaptW;
    else if (z < 7)  src = kW + (size_t)(z - 1) * 65536;
    else if (z < 13) src = qW + (size_t)(z - 7) * 65536;
    else if (z < 19) src = vW + (size_t)(z - 13) * 65536;
    else             src = aW + (size_t)(z - 19) * 65536;
    unsigned short* dst = WT + (size_t)z * 65536;
    __shared__ float tile[32][33];
    int tx = threadIdx.x & 31, ty = threadIdx.x >> 5;
    int kb = blockIdx.x * 32, cb = blockIdx.y * 32;
    #pragma unroll
    for (int i = 0; i < 4; ++i)
        tile[ty + i * 8][tx] = src[(size_t)(kb + ty + i * 8) * 256 + cb + tx];
    __syncthreads();
    #pragma unroll
    for (int i = 0; i < 4; ++i)
        dst[(size_t)(cb + ty + i * 8) * 256 + kb + tx] = f2bf(tile[tx][ty + i * 8]);
}

// ---------- MFMA GEMM ----------
#define AIDX(row, kb) (((row) << 6) + ((((kb) ^ (((row) & 7) << 4))) >> 1))
__global__ __launch_bounds__(256) void gemm_mfma(
    const float* __restrict__ A, const int* __restrict__ gidx,
    const unsigned short* __restrict__ WT, int wStride,
    const float* __restrict__ b0, const float* __restrict__ b1, const float* __restrict__ b2,
    void* __restrict__ o0, void* __restrict__ o1, void* __restrict__ o2,
    int n, float inScale, int outBf16)
{
    __shared__ unsigned short As[64 * 64];
    __shared__ unsigned short Bs[64 * 64];
    const int z = blockIdx.z;
    const unsigned short* W = WT + (size_t)z * wStride;
    const float* bias = (z == 0) ? b0 : ((z == 1) ? b1 : b2);
    void* outp = (z == 0) ? o0 : ((z == 1) ? o1 : o2);
    const int tid = threadIdx.x;
    const int rowBase = blockIdx.x * 64, colBase = blockIdx.y * 64;
    const int lr = tid >> 2, lq = tid & 3;
    const int arow = rowBase + lr;
    const bool aval = arow < n;
    const int ar = aval ? (gidx ? gidx[arow] : arow) : 0;
    const float* Ap = A + (size_t)ar * 256 + lq * 16;
    const unsigned short* Bp = W + (size_t)(colBase + lr) * 256 + lq * 16;
    const int lane = tid & 63, wv = tid >> 6;
    const int fr = lane & 15, fg = lane >> 4;
    const int wrow = (wv & 1) * 32, wcol = (wv >> 1) * 32;
    f32x4 acc[2][2];
    #pragma unroll
    for (int m = 0; m < 2; ++m)
        #pragma unroll
        for (int nn = 0; nn < 2; ++nn) acc[m][nn] = 0.f;

    for (int ks = 0; ks < 4; ++ks) {
        float4 a0 = make_float4(0,0,0,0), a1 = a0, a2 = a0, a3 = a0;
        if (aval) {
            a0 = *reinterpret_cast<const float4*>(Ap + ks * 64 + 0);
            a1 = *reinterpret_cast<const float4*>(Ap + ks * 64 + 4);
            a2 = *reinterpret_cast<const float4*>(Ap + ks * 64 + 8);
            a3 = *reinterpret_cast<const float4*>(Ap + ks * 64 + 12);
        }
        u16x8 bv0 = *reinterpret_cast<const u16x8*>(Bp + ks * 64);
        u16x8 bv1 = *reinterpret_cast<const u16x8*>(Bp + ks * 64 + 8);
        u16x8 pa0, pa1;
        pa0[0] = f2bf(a0.x * inScale); pa0[1] = f2bf(a0.y * inScale);
        pa0[2] = f2bf(a0.z * inScale); pa0[3] = f2bf(a0.w * inScale);
        pa0[4] = f2bf(a1.x * inScale); pa0[5] = f2bf(a1.y * inScale);
        pa0[6] = f2bf(a1.z * inScale); pa0[7] = f2bf(a1.w * inScale);
        pa1[0] = f2bf(a2.x * inScale); pa1[1] = f2bf(a2.y * inScale);
        pa1[2] = f2bf(a2.z * inScale); pa1[3] = f2bf(a2.w * inScale);
        pa1[4] = f2bf(a3.x * inScale); pa1[5] = f2bf(a3.y * inScale);
        pa1[6] = f2bf(a3.z * inScale); pa1[7] = f2bf(a3.w * inScale);
        __syncthreads();
        *reinterpret_cast<u16x8*>(&As[AIDX(lr, lq * 32)])      = pa0;
        *reinterpret_cast<u16x8*>(&As[AIDX(lr, lq * 32 + 16)]) = pa1;
        *reinterpret_cast<u16x8*>(&Bs[AIDX(lr, lq * 32)])      = bv0;
        *reinterpret_cast<u16x8*>(&Bs[AIDX(lr, lq * 32 + 16)]) = bv1;
        __syncthreads();
        #pragma unroll
        for (int kk = 0; kk < 2; ++kk) {
            bf16x8 af0 = *reinterpret_cast<bf16x8*>(&As[AIDX(wrow + fr,      kk * 64 + fg * 16)]);
            bf16x8 af1 = *reinterpret_cast<bf16x8*>(&As[AIDX(wrow + 16 + fr, kk * 64 + fg * 16)]);
            bf16x8 bf0 = *reinterpret_cast<bf16x8*>(&Bs[AIDX(wcol + fr,      kk * 64 + fg * 16)]);
            bf16x8 bf1 = *reinterpret_cast<bf16x8*>(&Bs[AIDX(wcol + 16 + fr, kk * 64 + fg * 16)]);
            acc[0][0] = __builtin_amdgcn_mfma_f32_16x16x32_bf16(af0, bf0, acc[0][0], 0, 0, 0);
            acc[0][1] = __builtin_amdgcn_mfma_f32_16x16x32_bf16(af0, bf1, acc[0][1], 0, 0, 0);
            acc[1][0] = __builtin_amdgcn_mfma_f32_16x16x32_bf16(af1, bf0, acc[1][0], 0, 0, 0);
            acc[1][1] = __builtin_amdgcn_mfma_f32_16x16x32_bf16(af1, bf1, acc[1][1], 0, 0, 0);
        }
    }
    #pragma unroll
    for (int m = 0; m < 2; ++m) {
        #pragma unroll
        for (int r = 0; r < 4; ++r) {
            int gr = rowBase + wrow + m * 16 + fg * 4 + r;
            if (gr >= n) continue;
            #pragma unroll
            for (int nn = 0; nn < 2; ++nn) {
                int gc = colBase + wcol + nn * 16 + fr;
                float v = acc[m][nn][r] + bias[gc];
                if (outBf16) ((unsigned short*)outp)[(size_t)gr * 256 + gc] = f2bf(v);
                else         ((float*)outp)[(size_t)gr * 256 + gc] = v;
            }
        }
    }
}

// ---------- batched block-diagonal transform for a dst-type group ----------
// grid: (maxRows/64, 8 heads, 2*nr); z -> rr = z>>1, isV = z&1. pri/sqrt(dk) folded into katt.
__global__ __launch_bounds__(256) void bd_group(
    unsigned short* __restrict__ katt, unsigned short* __restrict__ vmsg, BdArgs A)
{
    const int rr = blockIdx.z >> 1, isV = blockIdx.z & 1;
    const int n = A.rows[rr];
    const int rowBase = blockIdx.x * 64;
    if (rowBase >= n) return;
    const unsigned short* in = isV ? A.inV[rr] : A.inK[rr];
    const float* R = isV ? A.RM[rr] : A.RA[rr];
    unsigned short* out = (isV ? vmsg : katt) + (size_t)A.rowOfs[rr] * 256;
    const int head = blockIdx.y;
    const float oscale = isV ? 1.f : (A.priP[rr][head] * 0.17677669529663687f);
    __shared__ float As[64 * 33];
    __shared__ float Rs[32 * 33];
    const int tid = threadIdx.x;
    {
        int row = tid >> 2, q = tid & 3;
        int r = rowBase + row;
        u16x8 v = {};
        if (r < n) v = *reinterpret_cast<const u16x8*>(in + (size_t)r * 256 + head * 32 + q * 8);
        float* ap = &As[row * 33 + q * 8];
        #pragma unroll
        for (int j = 0; j < 8; ++j) ap[j] = bfd(v[j]);
    }
    {
        int k = tid >> 3, l0 = (tid & 7) * 4;
        float4 rv = *reinterpret_cast<const float4*>(R + head * 1024 + k * 32 + l0);
        float* rp = &Rs[k * 33 + l0];
        rp[0] = rv.x; rp[1] = rv.y; rp[2] = rv.z; rp[3] = rv.w;
    }
    __syncthreads();
    const int wv = tid >> 6, lane = tid & 63;
    float acc[8] = {0.f, 0.f, 0.f, 0.f, 0.f, 0.f, 0.f, 0.f};
    #pragma unroll
    for (int k = 0; k < 32; ++k) {
        float a = As[lane * 33 + k];
        const float* rp = &Rs[k * 33 + wv * 8];
        #pragma unroll
        for (int j = 0; j < 8; ++j) acc[j] += a * rp[j];
    }
    int r = rowBase + lane;
    if (r < n) {
        ushort4 o0, o1;
        o0.x = f2bf(acc[0] * oscale); o0.y = f2bf(acc[1] * oscale);
        o0.z = f2bf(acc[2] * oscale); o0.w = f2bf(acc[3] * oscale);
        o1.x = f2bf(acc[4] * oscale); o1.y = f2bf(acc[5] * oscale);
        o1.z = f2bf(acc[6] * oscale); o1.w = f2bf(acc[7] * oscale);
        ushort4* po = reinterpret_cast<ushort4*>(out + (size_t)r * 256 + head * 32 + wv * 8);
        po[0] = o0; po[1] = o1;
    }
}

// ---------- EK1 for a group: a = dot(q[dst][h], katt[src][h]) (pri folded) ----------
__global__ __launch_bounds__(256) void ek1_group(
    const unsigned short* __restrict__ qbuf, const unsigned short* __restrict__ katt,
    float* __restrict__ alog, Ek1Args A)
{
    const int rr = blockIdx.y;
    int gid = blockIdx.x * 256 + threadIdx.x;
    int e = gid >> 3, h = gid & 7;
    if (e >= A.E[rr]) return;
    int s = A.src[rr][e], d = A.dst[rr][e];
    const u16x8* q8 = reinterpret_cast<const u16x8*>(qbuf + (size_t)d * 256 + h * 32);
    const u16x8* k8 = reinterpret_cast<const u16x8*>(katt + ((size_t)(A.rowOfs[rr] + s)) * 256 + h * 32);
    float a = 0.f;
    #pragma unroll
    for (int j = 0; j < 4; ++j) {
        u16x8 qv = q8[j], kv = k8[j];
        #pragma unroll
        for (int m = 0; m < 8; ++m) a += bfd(qv[m]) * bfd(kv[m]);
    }
    alog[(size_t)(A.eBase[rr] + e) * 8 + h] = a;
}

// ---------- EK3 for a group: wave per dst node, loops rels, writes tP (no memset) ----------
__global__ __launch_bounds__(256) void ek3_group(
    const unsigned short* __restrict__ vmsg, const float* __restrict__ alog,
    const int* __restrict__ rowptrAll, const int* __restrict__ eidxAll,
    const float* __restrict__ te7, float* __restrict__ tacc, Ek3Args A)
{
    __shared__ float sTe[224];
    if (threadIdx.x < 224) sTe[threadIdx.x] = te7[threadIdx.x];
    __syncthreads();
    int wv = threadIdx.x >> 6, lane = threadIdx.x & 63;
    int d = blockIdx.x * 4 + wv;
    if (d >= A.nD) return;
    int c = lane * 4, h = lane >> 3;
    float t0 = 0.f, t1 = 0.f, t2 = 0.f, t3 = 0.f;
    for (int rr = 0; rr < A.nr; ++rr) {
        int base = A.dstBase[rr] + d;
        int beg = rowptrAll[base], end = rowptrAll[base + 1];
        if (beg == end) continue;
        float m = -INFINITY;
        for (int p = beg; p < end; ++p) m = fmaxf(m, alog[(size_t)eidxAll[p] * 8 + h]);
        float den = 0.f, a0 = 0.f, a1 = 0.f, a2 = 0.f, a3 = 0.f;
        const int* srcp = A.src[rr];
        const int* timp = A.tim[rr];
        int eB = A.eBase[rr], rO = A.rowOfs[rr];
        for (int p = beg; p < end; ++p) {
            int ge = eidxAll[p];
            int le = ge - eB;
            int s = srcp[le];
            float ex = __expf(alog[(size_t)ge * 8 + h] - m);
            den += ex;
            ushort4 v = *reinterpret_cast<const ushort4*>(vmsg + ((size_t)(rO + s)) * 256 + c);
            float vx = bfd(v.x), vy = bfd(v.y), vz = bfd(v.z), vw = bfd(v.w);
            if (timp) {
                const float* tp = &sTe[timp[le] * 32 + (c & 31)];
                vx += tp[0]; vy += tp[1]; vz += tp[2]; vw += tp[3];
            }
            a0 += ex * vx; a1 += ex * vy; a2 += ex * vz; a3 += ex * vw;
        }
        float inv = 1.f / fmaxf(den, 1e-9f);
        t0 += fmaxf(a0 * inv, 0.f); t1 += fmaxf(a1 * inv, 0.f);
        t2 += fmaxf(a2 * inv, 0.f); t3 += fmaxf(a3 * inv, 0.f);
    }
    *reinterpret_cast<float4*>(tacc + (size_t)d * 256 + c) = make_float4(t0, t1, t2, t3);
}

// ---------- fused CSR build ----------
__global__ void count_all(CsrArgs A, int* __restrict__ cnt, int totE) {
    int gid = blockIdx.x * 256 + threadIdx.x;
    if (gid >= totE) return;
    int r = 0;
    while (gid >= A.relOfs[r + 1]) ++r;
    int e = gid - A.relOfs[r];
    atomicAdd(&cnt[A.dstBase[r] + A.dst[r][e]], 1);
}
__global__ __launch_bounds__(1024) void scan1_k(const int* __restrict__ cnt, int* __restrict__ part,
                                                int* __restrict__ bsum, int n) {
    __shared__ int buf[1024];
    int tid = threadIdx.x, gid = blockIdx.x * 1024 + tid;
    int x = (gid < n) ? cnt[gid] : 0;
    buf[tid] = x; __syncthreads();
    for (int off = 1; off < 1024; off <<= 1) {
        int y = (tid >= off) ? buf[tid - off] : 0;
        __syncthreads();
        buf[tid] += y;
        __syncthreads();
    }
    if (gid < n) part[gid] = buf[tid];
    if (tid == 1023) bsum[blockIdx.x] = buf[1023];
}
__global__ __launch_bounds__(256) void scan2_k(int* __restrict__ bsum, int nb) {
    __shared__ int buf[256];
    int tid = threadIdx.x;
    buf[tid] = (tid < nb) ? bsum[tid] : 0;
    __syncthreads();
    for (int off = 1; off < 256; off <<= 1) {
        int y = (tid >= off) ? buf[tid - off] : 0;
        __syncthreads();
        buf[tid] += y;
        __syncthreads();
    }
    if (tid < nb) bsum[tid] = buf[tid];
}
__global__ void scan3_k(const int* __restrict__ cnt, const int* __restrict__ part,
                        const int* __restrict__ bsum, int* __restrict__ rowptr,
                        int* __restrict__ cur, int n) {
    int gid = blockIdx.x * 256 + threadIdx.x;
    if (gid < n) {
        int b = gid >> 10;
        int add = (b > 0) ? bsum[b - 1] : 0;
        int inc = part[gid] + add;
        rowptr[gid + 1] = inc;
        cur[gid] = inc - cnt[gid];
    }
    if (gid == 0) rowptr[0] = 0;
}
__global__ void scatter_all(CsrArgs A, int* __restrict__ cur, int* __restrict__ eidx, int totE) {
    int gid = blockIdx.x * 256 + threadIdx.x;
    if (gid >= totE) return;
    int r = 0;
    while (gid >= A.relOfs[r + 1]) ++r;
    int e = gid - A.relOfs[r];
    int p = atomicAdd(&cur[A.dstBase[r] + A.dst[r][e]], 1);
    eidx[p] = gid;
}

// ---------- skip-mix + layernorm ----------
__global__ __launch_bounds__(256) void mix_ln(
    float* __restrict__ h, const float* __restrict__ trans, const float* __restrict__ skipP,
    const float* __restrict__ g, const float* __restrict__ b, int n)
{
    int row = blockIdx.x;
    if (row >= n) return;
    int c = threadIdx.x;
    float alpha = 1.f / (1.f + expf(-skipP[0]));
    size_t off = (size_t)row * 256 + c;
    float o = trans[off] * alpha + h[off] * (1.f - alpha);
    float s = o, ss = o * o;
    #pragma unroll
    for (int d = 1; d < 64; d <<= 1) { s += __shfl_xor(s, d); ss += __shfl_xor(ss, d); }
    __shared__ float rS[4], rSS[4];
    int w = threadIdx.x >> 6, lane = threadIdx.x & 63;
    if (lane == 0) { rS[w] = s; rSS[w] = ss; }
    __syncthreads();
    float S = rS[0] + rS[1] + rS[2] + rS[3];
    float SS = rSS[0] + rSS[1] + rSS[2] + rSS[3];
    float mean = S * (1.f / 256.f);
    float var = fmaxf(SS * (1.f / 256.f) - mean * mean, 0.f);
    float rs = rsqrtf(var + 1e-5f);
    h[off] = (o - mean) * rs * g[c] + b[c];
}

// ---------- group max: chunked rows, register run-max, encoded atomicMax ----------
__global__ __launch_bounds__(256) void gmax_all(GmaxArgs A, unsigned* __restrict__ gi) {
    int ty = blockIdx.y;
    int n = A.n[ty];
    int r0 = blockIdx.x * 64;
    if (r0 >= n) return;
    int col = threadIdx.x;
    const float* hp = A.hp[ty];
    const int* grp = A.grp[ty];
    int cbase = A.colBase[ty];
    int rend = (r0 + 64 < n) ? r0 + 64 : n;
    int cur = grp[r0];
    float m = -INFINITY;
    for (int r = r0; r < rend; ++r) {
        int g = grp[r];
        if (g != cur) {
            atomicMax(&gi[cur * 768 + cbase + col], encf(m));
            cur = g; m = -INFINITY;
        }
        m = fmaxf(m, hp[(size_t)r * 256 + col]);
    }
    atomicMax(&gi[cur * 768 + cbase + col], encf(m));
}

__global__ void gi_init(unsigned* __restrict__ gi) {
    int i = blockIdx.x * 256 + threadIdx.x;
    if (i < 16 * 768) gi[i] = 0x007FFFFFu;  // encf(-inf)
}

// ---------- final: logits, loss, sigmoid ----------
__global__ __launch_bounds__(1024) void final_k(const unsigned* __restrict__ gi,
                                                const float* __restrict__ out_w,
                                                const float* __restrict__ out_b,
                                                const float* __restrict__ y,
                                                float* __restrict__ out) {
    int w = threadIdx.x >> 6, lane = threadIdx.x & 63;
    float s = 0.f;
    for (int c = lane; c < 768; c += 64) s += decf(gi[w * 768 + c]) * out_w[c];
    #pragma unroll
    for (int d = 1; d < 64; d <<= 1) s += __shfl_xor(s, d);
    __shared__ float lloss[16];
    if (lane == 0) {
        float z = s + out_b[0];
        out[1 + w] = 1.f / (1.f + expf(-z));
        lloss[w] = fmaxf(z, 0.f) - z * y[w] + log1pf(expf(-fabsf(z)));
    }
    __syncthreads();
    if (threadIdx.x == 0) {
        float L = 0.f;
        for (int g2 = 0; g2 < 16; ++g2) L += lloss[g2];
        out[0] = L * (1.f / 16.f);
    }
}

extern "C" void kernel_launch(void* const* d_in, const int* in_sizes, int n_in,
                              void* d_out, int out_size, void* d_ws, size_t ws_size,
                              hipStream_t stream) {
    const int* word_id   = (const int*)d_in[0];
    const int* topic_id  = (const int*)d_in[1];
    const int* g_word    = (const int*)d_in[2];
    const int* g_topic   = (const int*)d_in[3];
    const int* g_doc     = (const int*)d_in[4];
    const int* src_ww = (const int*)d_in[5];  const int* dst_ww = (const int*)d_in[6];  const int* time_ww = (const int*)d_in[7];
    const int* src_wd = (const int*)d_in[8];  const int* dst_wd = (const int*)d_in[9];  const int* time_wd = (const int*)d_in[10];
    const int* src_wt = (const int*)d_in[11]; const int* dst_wt = (const int*)d_in[12]; const int* time_wt = (const int*)d_in[13];
    const int* src_td = (const int*)d_in[14]; const int* dst_td = (const int*)d_in[15]; const int* time_td = (const int*)d_in[16];
    const int* src_tt = (const int*)d_in[17]; const int* dst_tt = (const int*)d_in[18];
    const float* y_data      = (const float*)d_in[19];
    const float* word_embeds = (const float*)d_in[20];
    const float* topic_embeds= (const float*)d_in[21];
    const float* doc_gen     = (const float*)d_in[22];
    const float* adapt_w     = (const float*)d_in[23];
    const float* adapt_b     = (const float*)d_in[24];
    const float* time_tab    = (const float*)d_in[25];
    const float* time_w      = (const float*)d_in[26];
    const float* time_b      = (const float*)d_in[27];
    const float* kW = (const float*)d_in[28];
    const float* qW = (const float*)d_in[29];
    const float* vW = (const float*)d_in[30];
    const float* aW = (const float*)d_in[31];
    const float* kB = (const float*)d_in[32];
    const float* qB = (const float*)d_in[33];
    const float* vB = (const float*)d_in[34];
    const float* aB = (const float*)d_in[35];
    const float* skip = (const float*)d_in[36];
    const float* ln_g = (const float*)d_in[37];
    const float* ln_b = (const float*)d_in[38];
    const float* pri  = (const float*)d_in[39];
    const float* attR = (const float*)d_in[40];
    const float* msgR = (const float*)d_in[41];
    const float* out_w = (const float*)d_in[42];
    const float* out_b = (const float*)d_in[43];

    const int NW = in_sizes[0], NT = in_sizes[1], ND = in_sizes[4];
    const int E_ww = in_sizes[5], E_wd = in_sizes[8], E_wt = in_sizes[11],
              E_td = in_sizes[14], E_tt = in_sizes[17];
    const int nN[3] = {NW, NT, ND};
    const float invNin[3] = {1.f / 3.f, 1.f / 3.f, 1.f / 2.f};

    struct Rel { int e, s, d; const int* src; const int* dst; const int* tim; int E; };
    const Rel rels[8] = {
        {0, 0, 1, src_wt, dst_wt, time_wt, E_wt},
        {1, 0, 2, src_wd, dst_wd, time_wd, E_wd},
        {2, 1, 2, src_td, dst_td, time_td, E_td},
        {3, 1, 1, src_tt, dst_tt, nullptr, E_tt},
        {4, 0, 0, src_ww, dst_ww, time_ww, E_ww},
        {5, 1, 0, dst_wt, src_wt, time_wt, E_wt},
        {6, 2, 1, dst_td, src_td, time_td, E_td},
        {7, 2, 0, dst_wd, src_wd, time_wd, E_wd},
    };

    // prefix tables
    int relOfs[9]; relOfs[0] = 0;
    int dstBase[8]; int acc = 0;
    for (int r = 0; r < 8; ++r) { relOfs[r + 1] = relOfs[r] + rels[r].E; dstBase[r] = acc; acc += nN[rels[r].d]; }
    const int totE = relOfs[8], totD = acc;

    // groups by dst type: word <- {4,5,7}, topic <- {0,3,6}, doc <- {1,2}
    const int grpRels[3][3] = {{4, 5, 7}, {0, 3, 6}, {1, 2, 0}};
    const int nrG[3] = {3, 3, 2};
    int rowOfsG[3][3], grpRows[3];
    for (int g = 0; g < 3; ++g) {
        int ro = 0;
        for (int j = 0; j < nrG[g]; ++j) { rowOfsG[g][j] = ro; ro += nN[rels[grpRels[g][j]].s]; }
        grpRows[g] = ro;
    }
    int maxGrpRows = 0;
    for (int g = 0; g < 3; ++g) if (grpRows[g] > maxGrpRows) maxGrpRows = grpRows[g];

    // ---- workspace carve-up (units of float) ----
    float* base = (float*)d_ws;
    size_t off = 0;
    auto take = [&](size_t nElems) { float* p = base + off; off += (nElems + 63) & ~(size_t)63; return p; };
    float* hP[3]; float* tP[3];
    unsigned short* kP[3]; unsigned short* qP[3]; unsigned short* vP[3];
    for (int i = 0; i < 3; ++i) hP[i] = take((size_t)nN[i] * 256);
    for (int i = 0; i < 3; ++i) tP[i] = take((size_t)nN[i] * 256);
    for (int i = 0; i < 3; ++i) kP[i] = (unsigned short*)take((size_t)nN[i] * 128);
    for (int i = 0; i < 3; ++i) qP[i] = (unsigned short*)take((size_t)nN[i] * 128);
    for (int i = 0; i < 3; ++i) vP[i] = (unsigned short*)take((size_t)nN[i] * 128);
    // katt+vmsg (bf16, group-sized); trans (f32) aliases the pair after rels are done
    unsigned short* kattB = (unsigned short*)take((size_t)maxGrpRows * 128);
    unsigned short* vmsgB = (unsigned short*)take((size_t)maxGrpRows * 128);
    float* trans = (float*)kattB;   // maxGrpRows*256*2B*2 >= NW*256*4B holds for this graph
    unsigned short* WT = (unsigned short*)take((size_t)25 * 32768);
    float* alog = take((size_t)totE * 8);
    float* te7  = take(7 * 32);
    unsigned* gi = (unsigned*)take(16 * 768);
    int* cntAll = (int*)take(totD);
    int* part   = (int*)take(totD);
    int* bsum   = (int*)take(256);
    int* rowptrAll = (int*)take(totD + 1);
    int* curAll = (int*)take(totD);
    int* eidxAll = (int*)take(totE);
    (void)ws_size; (void)n_in; (void)out_size;

    // ---- setup: te table, weights, CSR, gi init ----
    te_kernel<<<1, 256, 0, stream>>>(time_tab, time_w, time_b, te7);
    {
        dim3 g(8, 8, 25);
        wtr_kernel<<<g, 256, 0, stream>>>(adapt_w, kW, qW, vW, aW, WT);
    }
    CsrArgs ca;
    for (int r = 0; r < 8; ++r) { ca.dst[r] = rels[r].dst; ca.dstBase[r] = dstBase[r]; }
    for (int r = 0; r < 9; ++r) ca.relOfs[r] = relOfs[r];
    hipMemsetAsync(cntAll, 0, (size_t)totD * sizeof(int), stream);
    count_all<<<(totE + 255) / 256, 256, 0, stream>>>(ca, cntAll, totE);
    int nb = (totD + 1023) / 1024;
    scan1_k<<<nb, 1024, 0, stream>>>(cntAll, part, bsum, totD);
    scan2_k<<<1, 256, 0, stream>>>(bsum, nb);
    scan3_k<<<(totD + 255) / 256, 256, 0, stream>>>(cntAll, part, bsum, rowptrAll, curAll, totD);
    scatter_all<<<(totE + 255) / 256, 256, 0, stream>>>(ca, curAll, eidxAll, totE);
    gi_init<<<48, 256, 0, stream>>>(gi);

    // ---- init node features ----
    {
        dim3 g((NW + 63) / 64, 4, 1);
        gemm_mfma<<<g, 256, 0, stream>>>(word_embeds, word_id, WT, 0,
                                         adapt_b, adapt_b, adapt_b,
                                         hP[0], hP[0], hP[0], NW, 1.f, 0);
    }
    gather_rows<<<NT, 256, 0, stream>>>(topic_embeds, topic_id, hP[1], NT);
    bcast_row<<<ND, 256, 0, stream>>>(doc_gen, hP[2], ND);

    // group arg structs (layer-independent parts)
    Ek1Args e1a[3]; Ek3Args e3a[3];
    int maxE_g[3];
    for (int g = 0; g < 3; ++g) {
        int me = 0;
        for (int j = 0; j < 3; ++j) {
            int jr = (j < nrG[g]) ? grpRels[g][j] : grpRels[g][0];
            const Rel& R = rels[jr];
            e1a[g].src[j] = R.src; e1a[g].dst[j] = R.dst;
            e1a[g].E[j] = (j < nrG[g]) ? R.E : 0;
            e1a[g].eBase[j] = relOfs[jr];
            e1a[g].rowOfs[j] = (j < nrG[g]) ? rowOfsG[g][j] : 0;
            e3a[g].src[j] = R.src; e3a[g].tim[j] = R.tim;
            e3a[g].eBase[j] = relOfs[jr]; e3a[g].dstBase[j] = dstBase[jr];
            e3a[g].rowOfs[j] = (j < nrG[g]) ? rowOfsG[g][j] : 0;
            if (j < nrG[g] && R.E > me) me = R.E;
        }
        e3a[g].nr = nrG[g]; e3a[g].nD = nN[g];
        maxE_g[g] = me;
    }

    // ---- layers ----
    for (int li = 0; li < LNUM; ++li) {
        for (int i = 0; i < 3; ++i) {
            int j = li * 3 + i;
            dim3 g((nN[i] + 63) / 64, 4, 3);
            gemm_mfma<<<g, 256, 0, stream>>>(hP[i], nullptr, WT + (size_t)(1 + j) * 65536, 6 * 65536,
                                             kB + (size_t)j * 256, qB + (size_t)j * 256, vB + (size_t)j * 256,
                                             kP[i], qP[i], vP[i], nN[i], 1.f, 1);
        }

        for (int g = 0; g < 3; ++g) {
            BdArgs ba;
            int maxRows = 0;
            for (int j = 0; j < 3; ++j) {
                int jr = (j < nrG[g]) ? grpRels[g][j] : grpRels[g][0];
                const Rel& R = rels[jr];
                ba.inK[j] = kP[R.s]; ba.inV[j] = vP[R.s];
                ba.RA[j] = attR + ((size_t)li * 8 + R.e) * 8192;
                ba.RM[j] = msgR + ((size_t)li * 8 + R.e) * 8192;
                ba.priP[j] = pri + ((size_t)li * 8 + R.e) * 8;
                ba.rows[j] = (j < nrG[g]) ? nN[R.s] : 0;
                ba.rowOfs[j] = (j < nrG[g]) ? rowOfsG[g][j] : 0;
                if (ba.rows[j] > maxRows) maxRows = ba.rows[j];
            }
            dim3 gb((maxRows + 63) / 64, 8, 2 * nrG[g]);
            bd_group<<<gb, 256, 0, stream>>>(kattB, vmsgB, ba);
            dim3 g1((maxE_g[g] * 8 + 255) / 256, nrG[g]);
            ek1_group<<<g1, 256, 0, stream>>>(qP[g], kattB, alog, e1a[g]);
            ek3_group<<<(nN[g] + 3) / 4, 256, 0, stream>>>(vmsgB, alog, rowptrAll, eidxAll,
                                                           te7, tP[g], e3a[g]);
        }

        for (int i = 0; i < 3; ++i) {
            int j = li * 3 + i;
            dim3 g((nN[i] + 63) / 64, 4, 1);
            gemm_mfma<<<g, 256, 0, stream>>>(tP[i], nullptr, WT + (size_t)(19 + j) * 65536, 0,
                                             aB + (size_t)j * 256, aB + (size_t)j * 256, aB + (size_t)j * 256,
                                             trans, trans, trans, nN[i], invNin[i], 0);
            mix_ln<<<nN[i], 256, 0, stream>>>(hP[i], trans, skip + (size_t)j,
                                              ln_g + (size_t)j * 256, ln_b + (size_t)j * 256, nN[i]);
        }
    }

    // ---- readout ----
    GmaxArgs ga;
    ga.hp[0] = hP[2]; ga.grp[0] = g_doc;   ga.n[0] = ND; ga.colBase[0] = 0;
    ga.hp[1] = hP[0]; ga.grp[1] = g_word;  ga.n[1] = NW; ga.colBase[1] = 256;
    ga.hp[2] = hP[1]; ga.grp[2] = g_topic; ga.n[2] = NT; ga.colBase[2] = 512;
    int maxN = NW > ND ? (NW > NT ? NW : NT) : (ND > NT ? ND : NT);
    dim3 gg((maxN + 63) / 64, 3);
    gmax_all<<<gg, 256, 0, stream>>>(ga, gi);
    final_k<<<1, 1024, 0, stream>>>(gi, out_w, out_b, y_data, (float*)d_out);
}

// Round 5
// 908.962 us; speedup vs baseline: 9.4312x; 1.1202x over previous
//
#include <hip/hip_runtime.h>
#include <hip/hip_bf16.h>
#include <math.h>

#define H 8
#define DK 32
#define NHID 256
#define LNUM 2
#define GNUM 16

typedef float f32x4 __attribute__((ext_vector_type(4)));
typedef short bf16x8 __attribute__((ext_vector_type(8)));
typedef unsigned short u16x8 __attribute__((ext_vector_type(8)));

__device__ __forceinline__ unsigned encf(float f) {
    unsigned u = __float_as_uint(f);
    return (u & 0x80000000u) ? ~u : (u | 0x80000000u);
}
__device__ __forceinline__ float decf(unsigned u) {
    return __uint_as_float((u & 0x80000000u) ? (u ^ 0x80000000u) : ~u);
}
__device__ __forceinline__ float bfd(unsigned short u) {
    return __uint_as_float(((unsigned)u) << 16);
}
__device__ __forceinline__ unsigned short f2bf(float x) {
    __hip_bfloat16 b = __float2bfloat16(x);
    return *reinterpret_cast<unsigned short*>(&b);
}

// ---------- by-value arg structs ----------
struct CsrArgs { const int* dst[8]; int relOfs[9]; int dstBase[8]; };
struct BdArgs  { const unsigned short* inK[3]; const unsigned short* inV[3];
                 const float* RA[3]; const float* RM[3]; const float* priP[3];
                 int rows[3]; int rowOfs[3]; };
struct Ek1Args { const int* src[3]; const int* dst[3]; int E[3]; int eBase[3]; int rowOfs[3]; };
struct Ek3Args { const int* src[3]; const int* tim[3]; int eBase[3]; int dstBase[3];
                 int rowOfs[3]; int nr; int nD; };
struct GmaxArgs{ const float* hp[3]; const int* grp[3]; int n[3]; int colBase[3]; };

// ---------- temporal encoding table ----------
__global__ void te_kernel(const float* __restrict__ time_tab, const float* __restrict__ time_w,
                          const float* __restrict__ time_b, float* __restrict__ te7) {
    int t = threadIdx.x >> 5, j = threadIdx.x & 31;
    if (t < 7) {
        float s = time_b[j];
        #pragma unroll
        for (int i = 0; i < 32; ++i) s += time_tab[t * 32 + i] * time_w[i * 32 + j];
        te7[t * 32 + j] = s;
    }
}

__global__ void gather_rows(const float* __restrict__ emb, const int* __restrict__ idx,
                            float* __restrict__ out, int n) {
    int row = blockIdx.x, c = threadIdx.x;
    if (row < n) out[(size_t)row * 256 + c] = emb[(size_t)idx[row] * 256 + c];
}

__global__ void bcast_row(const float* __restrict__ src, float* __restrict__ out, int n) {
    int row = blockIdx.x, c = threadIdx.x;
    if (row < n) out[(size_t)row * 256 + c] = src[c];
}

// ---------- weight transpose+bf16 ----------
__global__ __launch_bounds__(256) void wtr_kernel(
    const float* __restrict__ adaptW, const float* __restrict__ kW, const float* __restrict__ qW,
    const float* __restrict__ vW, const float* __restrict__ aW, unsigned short* __restrict__ WT) {
    int z = blockIdx.z;
    const float* src;
    if (z == 0) src = adaptW;
    else if (z < 7)  src = kW + (size_t)(z - 1) * 65536;
    else if (z < 13) src = qW + (size_t)(z - 7) * 65536;
    else if (z < 19) src = vW + (size_t)(z - 13) * 65536;
    else             src = aW + (size_t)(z - 19) * 65536;
    unsigned short* dst = WT + (size_t)z * 65536;
    __shared__ float tile[32][33];
    int tx = threadIdx.x & 31, ty = threadIdx.x >> 5;
    int kb = blockIdx.x * 32, cb = blockIdx.y * 32;
    #pragma unroll
    for (int i = 0; i < 4; ++i)
        tile[ty + i * 8][tx] = src[(size_t)(kb + ty + i * 8) * 256 + cb + tx];
    __syncthreads();
    #pragma unroll
    for (int i = 0; i < 4; ++i)
        dst[(size_t)(cb + ty + i * 8) * 256 + kb + tx] = f2bf(tile[tx][ty + i * 8]);
}

// ---------- MFMA GEMM ----------
#define AIDX(row, kb) (((row) << 6) + ((((kb) ^ (((row) & 7) << 4))) >> 1))
__global__ __launch_bounds__(256) void gemm_mfma(
    const float* __restrict__ A, const int* __restrict__ gidx,
    const unsigned short* __restrict__ WT, int wStride,
    const float* __restrict__ b0, const float* __restrict__ b1, const float* __restrict__ b2,
    void* __restrict__ o0, void* __restrict__ o1, void* __restrict__ o2,
    int n, float inScale, int outBf16)
{
    __shared__ unsigned short As[64 * 64];
    __shared__ unsigned short Bs[64 * 64];
    const int z = blockIdx.z;
    const unsigned short* W = WT + (size_t)z * wStride;
    const float* bias = (z == 0) ? b0 : ((z == 1) ? b1 : b2);
    void* outp = (z == 0) ? o0 : ((z == 1) ? o1 : o2);
    const int tid = threadIdx.x;
    const int rowBase = blockIdx.x * 64, colBase = blockIdx.y * 64;
    const int lr = tid >> 2, lq = tid & 3;
    const int arow = rowBase + lr;
    const bool aval = arow < n;
    const int ar = aval ? (gidx ? gidx[arow] : arow) : 0;
    const float* Ap = A + (size_t)ar * 256 + lq * 16;
    const unsigned short* Bp = W + (size_t)(colBase + lr) * 256 + lq * 16;
    const int lane = tid & 63, wv = tid >> 6;
    const int fr = lane & 15, fg = lane >> 4;
    const int wrow = (wv & 1) * 32, wcol = (wv >> 1) * 32;
    f32x4 acc[2][2];
    #pragma unroll
    for (int m = 0; m < 2; ++m)
        #pragma unroll
        for (int nn = 0; nn < 2; ++nn) acc[m][nn] = 0.f;

    for (int ks = 0; ks < 4; ++ks) {
        float4 a0 = make_float4(0,0,0,0), a1 = a0, a2 = a0, a3 = a0;
        if (aval) {
            a0 = *reinterpret_cast<const float4*>(Ap + ks * 64 + 0);
            a1 = *reinterpret_cast<const float4*>(Ap + ks * 64 + 4);
            a2 = *reinterpret_cast<const float4*>(Ap + ks * 64 + 8);
            a3 = *reinterpret_cast<const float4*>(Ap + ks * 64 + 12);
        }
        u16x8 bv0 = *reinterpret_cast<const u16x8*>(Bp + ks * 64);
        u16x8 bv1 = *reinterpret_cast<const u16x8*>(Bp + ks * 64 + 8);
        u16x8 pa0, pa1;
        pa0[0] = f2bf(a0.x * inScale); pa0[1] = f2bf(a0.y * inScale);
        pa0[2] = f2bf(a0.z * inScale); pa0[3] = f2bf(a0.w * inScale);
        pa0[4] = f2bf(a1.x * inScale); pa0[5] = f2bf(a1.y * inScale);
        pa0[6] = f2bf(a1.z * inScale); pa0[7] = f2bf(a1.w * inScale);
        pa1[0] = f2bf(a2.x * inScale); pa1[1] = f2bf(a2.y * inScale);
        pa1[2] = f2bf(a2.z * inScale); pa1[3] = f2bf(a2.w * inScale);
        pa1[4] = f2bf(a3.x * inScale); pa1[5] = f2bf(a3.y * inScale);
        pa1[6] = f2bf(a3.z * inScale); pa1[7] = f2bf(a3.w * inScale);
        __syncthreads();
        *reinterpret_cast<u16x8*>(&As[AIDX(lr, lq * 32)])      = pa0;
        *reinterpret_cast<u16x8*>(&As[AIDX(lr, lq * 32 + 16)]) = pa1;
        *reinterpret_cast<u16x8*>(&Bs[AIDX(lr, lq * 32)])      = bv0;
        *reinterpret_cast<u16x8*>(&Bs[AIDX(lr, lq * 32 + 16)]) = bv1;
        __syncthreads();
        #pragma unroll
        for (int kk = 0; kk < 2; ++kk) {
            bf16x8 af0 = *reinterpret_cast<bf16x8*>(&As[AIDX(wrow + fr,      kk * 64 + fg * 16)]);
            bf16x8 af1 = *reinterpret_cast<bf16x8*>(&As[AIDX(wrow + 16 + fr, kk * 64 + fg * 16)]);
            bf16x8 bf0 = *reinterpret_cast<bf16x8*>(&Bs[AIDX(wcol + fr,      kk * 64 + fg * 16)]);
            bf16x8 bf1 = *reinterpret_cast<bf16x8*>(&Bs[AIDX(wcol + 16 + fr, kk * 64 + fg * 16)]);
            acc[0][0] = __builtin_amdgcn_mfma_f32_16x16x32_bf16(af0, bf0, acc[0][0], 0, 0, 0);
            acc[0][1] = __builtin_amdgcn_mfma_f32_16x16x32_bf16(af0, bf1, acc[0][1], 0, 0, 0);
            acc[1][0] = __builtin_amdgcn_mfma_f32_16x16x32_bf16(af1, bf0, acc[1][0], 0, 0, 0);
            acc[1][1] = __builtin_amdgcn_mfma_f32_16x16x32_bf16(af1, bf1, acc[1][1], 0, 0, 0);
        }
    }
    #pragma unroll
    for (int m = 0; m < 2; ++m) {
        #pragma unroll
        for (int r = 0; r < 4; ++r) {
            int gr = rowBase + wrow + m * 16 + fg * 4 + r;
            if (gr >= n) continue;
            #pragma unroll
            for (int nn = 0; nn < 2; ++nn) {
                int gc = colBase + wcol + nn * 16 + fr;
                float v = acc[m][nn][r] + bias[gc];
                if (outBf16) ((unsigned short*)outp)[(size_t)gr * 256 + gc] = f2bf(v);
                else         ((float*)outp)[(size_t)gr * 256 + gc] = v;
            }
        }
    }
}

// ---------- batched block-diagonal transform for a dst-type group ----------
__global__ __launch_bounds__(256) void bd_group(
    unsigned short* __restrict__ katt, unsigned short* __restrict__ vmsg, BdArgs A)
{
    const int rr = blockIdx.z >> 1, isV = blockIdx.z & 1;
    const int n = A.rows[rr];
    const int rowBase = blockIdx.x * 64;
    if (rowBase >= n) return;
    const unsigned short* in = isV ? A.inV[rr] : A.inK[rr];
    const float* R = isV ? A.RM[rr] : A.RA[rr];
    unsigned short* out = (isV ? vmsg : katt) + (size_t)A.rowOfs[rr] * 256;
    const int head = blockIdx.y;
    const float oscale = isV ? 1.f : (A.priP[rr][head] * 0.17677669529663687f);
    __shared__ float As[64 * 33];
    __shared__ float Rs[32 * 33];
    const int tid = threadIdx.x;
    {
        int row = tid >> 2, q = tid & 3;
        int r = rowBase + row;
        u16x8 v = {};
        if (r < n) v = *reinterpret_cast<const u16x8*>(in + (size_t)r * 256 + head * 32 + q * 8);
        float* ap = &As[row * 33 + q * 8];
        #pragma unroll
        for (int j = 0; j < 8; ++j) ap[j] = bfd(v[j]);
    }
    {
        int k = tid >> 3, l0 = (tid & 7) * 4;
        float4 rv = *reinterpret_cast<const float4*>(R + head * 1024 + k * 32 + l0);
        float* rp = &Rs[k * 33 + l0];
        rp[0] = rv.x; rp[1] = rv.y; rp[2] = rv.z; rp[3] = rv.w;
    }
    __syncthreads();
    const int wv = tid >> 6, lane = tid & 63;
    float acc[8] = {0.f, 0.f, 0.f, 0.f, 0.f, 0.f, 0.f, 0.f};
    #pragma unroll
    for (int k = 0; k < 32; ++k) {
        float a = As[lane * 33 + k];
        const float* rp = &Rs[k * 33 + wv * 8];
        #pragma unroll
        for (int j = 0; j < 8; ++j) acc[j] += a * rp[j];
    }
    int r = rowBase + lane;
    if (r < n) {
        ushort4 o0, o1;
        o0.x = f2bf(acc[0] * oscale); o0.y = f2bf(acc[1] * oscale);
        o0.z = f2bf(acc[2] * oscale); o0.w = f2bf(acc[3] * oscale);
        o1.x = f2bf(acc[4] * oscale); o1.y = f2bf(acc[5] * oscale);
        o1.z = f2bf(acc[6] * oscale); o1.w = f2bf(acc[7] * oscale);
        ushort4* po = reinterpret_cast<ushort4*>(out + (size_t)r * 256 + head * 32 + wv * 8);
        po[0] = o0; po[1] = o1;
    }
}

// ---------- EK1 for a group ----------
__global__ __launch_bounds__(256) void ek1_group(
    const unsigned short* __restrict__ qbuf, const unsigned short* __restrict__ katt,
    float* __restrict__ alog, Ek1Args A)
{
    const int rr = blockIdx.y;
    int gid = blockIdx.x * 256 + threadIdx.x;
    int e = gid >> 3, h = gid & 7;
    if (e >= A.E[rr]) return;
    int s = A.src[rr][e], d = A.dst[rr][e];
    const u16x8* q8 = reinterpret_cast<const u16x8*>(qbuf + (size_t)d * 256 + h * 32);
    const u16x8* k8 = reinterpret_cast<const u16x8*>(katt + ((size_t)(A.rowOfs[rr] + s)) * 256 + h * 32);
    float a = 0.f;
    #pragma unroll
    for (int j = 0; j < 4; ++j) {
        u16x8 qv = q8[j], kv = k8[j];
        #pragma unroll
        for (int m = 0; m < 8; ++m) a += bfd(qv[m]) * bfd(kv[m]);
    }
    alog[(size_t)(A.eBase[rr] + e) * 8 + h] = a;
}

// ---------- EK3: wave per dst, single-pass online softmax, 8-edge wave-batched loads ----------
// Load layout: lane = b*8 + hl (b=edge-in-batch, hl=head). Accum layout: c=lane*4, h=lane>>3.
__global__ __launch_bounds__(256) void ek3_group(
    const unsigned short* __restrict__ vmsg, const float* __restrict__ alog,
    const int* __restrict__ rowptrAll, const int* __restrict__ eidxAll,
    const float* __restrict__ te7, float* __restrict__ tacc, Ek3Args A)
{
    __shared__ float sTe[224];
    if (threadIdx.x < 224) sTe[threadIdx.x] = te7[threadIdx.x];
    __syncthreads();
    int wv = threadIdx.x >> 6, lane = threadIdx.x & 63;
    int d = blockIdx.x * 4 + wv;
    if (d >= A.nD) return;
    const int bl = lane >> 3, hl = lane & 7;   // load layout
    const int c = lane * 4, hq = lane >> 3;    // accum layout
    float t0 = 0.f, t1 = 0.f, t2 = 0.f, t3 = 0.f;
    for (int rr = 0; rr < A.nr; ++rr) {
        int base = A.dstBase[rr] + d;
        int beg = rowptrAll[base], end = rowptrAll[base + 1];
        if (beg == end) continue;
        const int* srcp = A.src[rr];
        const int* timp = A.tim[rr];
        int eB = A.eBase[rr], rO = A.rowOfs[rr];
        float m = -INFINITY, den = 0.f;
        float a0 = 0.f, a1 = 0.f, a2 = 0.f, a3 = 0.f;
        for (int p0 = beg; p0 < end; p0 += 8) {
            int p = p0 + bl;
            bool valid = p < end;
            int ge = eidxAll[valid ? p : end - 1];
            int le = ge - eB;
            float a = valid ? alog[(size_t)ge * 8 + hl] : -INFINITY;
            int sS = valid ? srcp[le] : 0;
            int tT = (timp && valid) ? timp[le] : 0;
            // batch max over b (per hl)
            float bm = a;
            bm = fmaxf(bm, __shfl_xor(bm, 8));
            bm = fmaxf(bm, __shfl_xor(bm, 16));
            bm = fmaxf(bm, __shfl_xor(bm, 32));
            // to accum layout, update running max + rescale
            float bmA = __shfl(bm, hq);          // lane hq (<8) has hl==hq
            float mN = fmaxf(m, bmA);
            float sc = __expf(m - mN);           // m=-inf first time -> 0
            den *= sc; a0 *= sc; a1 *= sc; a2 *= sc; a3 *= sc;
            m = mN;
            // exp in load layout (needs mN for head hl -> lane hl*8 in accum layout)
            float mL = __shfl(mN, hl * 8);
            float ex = valid ? __expf(a - mL) : 0.f;
            // batch den sum per hl -> accum layout
            float ds = ex;
            ds += __shfl_xor(ds, 8);
            ds += __shfl_xor(ds, 16);
            ds += __shfl_xor(ds, 32);
            den += __shfl(ds, hq);
            // accumulate the (up to) 8 value rows
            int nb = end - p0; if (nb > 8) nb = 8;
            for (int b = 0; b < nb; ++b) {
                float w = __shfl(ex, b * 8 + hq);
                int sB = __shfl(sS, b * 8);
                ushort4 v = *reinterpret_cast<const ushort4*>(vmsg + ((size_t)(rO + sB)) * 256 + c);
                float vx = bfd(v.x), vy = bfd(v.y), vz = bfd(v.z), vw = bfd(v.w);
                if (timp) {
                    int tB = __shfl(tT, b * 8);
                    const float* tp = &sTe[tB * 32 + (c & 31)];
                    vx += tp[0]; vy += tp[1]; vz += tp[2]; vw += tp[3];
                }
                a0 += w * vx; a1 += w * vy; a2 += w * vz; a3 += w * vw;
            }
        }
        float inv = 1.f / fmaxf(den, 1e-9f);
        t0 += fmaxf(a0 * inv, 0.f); t1 += fmaxf(a1 * inv, 0.f);
        t2 += fmaxf(a2 * inv, 0.f); t3 += fmaxf(a3 * inv, 0.f);
    }
    *reinterpret_cast<float4*>(tacc + (size_t)d * 256 + c) = make_float4(t0, t1, t2, t3);
}

// ---------- fused CSR build ----------
__global__ void count_all(CsrArgs A, int* __restrict__ cnt, int totE) {
    int gid = blockIdx.x * 256 + threadIdx.x;
    if (gid >= totE) return;
    int r = 0;
    while (gid >= A.relOfs[r + 1]) ++r;
    int e = gid - A.relOfs[r];
    atomicAdd(&cnt[A.dstBase[r] + A.dst[r][e]], 1);
}
__global__ __launch_bounds__(1024) void scan1_k(const int* __restrict__ cnt, int* __restrict__ part,
                                                int* __restrict__ bsum, int n) {
    __shared__ int buf[1024];
    int tid = threadIdx.x, gid = blockIdx.x * 1024 + tid;
    int x = (gid < n) ? cnt[gid] : 0;
    buf[tid] = x; __syncthreads();
    for (int off = 1; off < 1024; off <<= 1) {
        int y = (tid >= off) ? buf[tid - off] : 0;
        __syncthreads();
        buf[tid] += y;
        __syncthreads();
    }
    if (gid < n) part[gid] = buf[tid];
    if (tid == 1023) bsum[blockIdx.x] = buf[1023];
}
__global__ __launch_bounds__(256) void scan2_k(int* __restrict__ bsum, int nb) {
    __shared__ int buf[256];
    int tid = threadIdx.x;
    buf[tid] = (tid < nb) ? bsum[tid] : 0;
    __syncthreads();
    for (int off = 1; off < 256; off <<= 1) {
        int y = (tid >= off) ? buf[tid - off] : 0;
        __syncthreads();
        buf[tid] += y;
        __syncthreads();
    }
    if (tid < nb) bsum[tid] = buf[tid];
}
__global__ void scan3_k(const int* __restrict__ cnt, const int* __restrict__ part,
                        const int* __restrict__ bsum, int* __restrict__ rowptr,
                        int* __restrict__ cur, int n) {
    int gid = blockIdx.x * 256 + threadIdx.x;
    if (gid < n) {
        int b = gid >> 10;
        int add = (b > 0) ? bsum[b - 1] : 0;
        int inc = part[gid] + add;
        rowptr[gid + 1] = inc;
        cur[gid] = inc - cnt[gid];
    }
    if (gid == 0) rowptr[0] = 0;
}
__global__ void scatter_all(CsrArgs A, int* __restrict__ cur, int* __restrict__ eidx, int totE) {
    int gid = blockIdx.x * 256 + threadIdx.x;
    if (gid >= totE) return;
    int r = 0;
    while (gid >= A.relOfs[r + 1]) ++r;
    int e = gid - A.relOfs[r];
    int p = atomicAdd(&cur[A.dstBase[r] + A.dst[r][e]], 1);
    eidx[p] = gid;
}

// ---------- skip-mix + layernorm ----------
__global__ __launch_bounds__(256) void mix_ln(
    float* __restrict__ h, const float* __restrict__ trans, const float* __restrict__ skipP,
    const float* __restrict__ g, const float* __restrict__ b, int n)
{
    int row = blockIdx.x;
    if (row >= n) return;
    int c = threadIdx.x;
    float alpha = 1.f / (1.f + expf(-skipP[0]));
    size_t off = (size_t)row * 256 + c;
    float o = trans[off] * alpha + h[off] * (1.f - alpha);
    float s = o, ss = o * o;
    #pragma unroll
    for (int d = 1; d < 64; d <<= 1) { s += __shfl_xor(s, d); ss += __shfl_xor(ss, d); }
    __shared__ float rS[4], rSS[4];
    int w = threadIdx.x >> 6, lane = threadIdx.x & 63;
    if (lane == 0) { rS[w] = s; rSS[w] = ss; }
    __syncthreads();
    float S = rS[0] + rS[1] + rS[2] + rS[3];
    float SS = rSS[0] + rSS[1] + rSS[2] + rSS[3];
    float mean = S * (1.f / 256.f);
    float var = fmaxf(SS * (1.f / 256.f) - mean * mean, 0.f);
    float rs = rsqrtf(var + 1e-5f);
    h[off] = (o - mean) * rs * g[c] + b[c];
}

// ---------- group max ----------
__global__ __launch_bounds__(256) void gmax_all(GmaxArgs A, unsigned* __restrict__ gi) {
    int ty = blockIdx.y;
    int n = A.n[ty];
    int r0 = blockIdx.x * 64;
    if (r0 >= n) return;
    int col = threadIdx.x;
    const float* hp = A.hp[ty];
    const int* grp = A.grp[ty];
    int cbase = A.colBase[ty];
    int rend = (r0 + 64 < n) ? r0 + 64 : n;
    int cur = grp[r0];
    float m = -INFINITY;
    for (int r = r0; r < rend; ++r) {
        int g = grp[r];
        if (g != cur) {
            atomicMax(&gi[cur * 768 + cbase + col], encf(m));
            cur = g; m = -INFINITY;
        }
        m = fmaxf(m, hp[(size_t)r * 256 + col]);
    }
    atomicMax(&gi[cur * 768 + cbase + col], encf(m));
}

__global__ void gi_init(unsigned* __restrict__ gi) {
    int i = blockIdx.x * 256 + threadIdx.x;
    if (i < 16 * 768) gi[i] = 0x007FFFFFu;  // encf(-inf)
}

// ---------- final ----------
__global__ __launch_bounds__(1024) void final_k(const unsigned* __restrict__ gi,
                                                const float* __restrict__ out_w,
                                                const float* __restrict__ out_b,
                                                const float* __restrict__ y,
                                                float* __restrict__ out) {
    int w = threadIdx.x >> 6, lane = threadIdx.x & 63;
    float s = 0.f;
    for (int c = lane; c < 768; c += 64) s += decf(gi[w * 768 + c]) * out_w[c];
    #pragma unroll
    for (int d = 1; d < 64; d <<= 1) s += __shfl_xor(s, d);
    __shared__ float lloss[16];
    if (lane == 0) {
        float z = s + out_b[0];
        out[1 + w] = 1.f / (1.f + expf(-z));
        lloss[w] = fmaxf(z, 0.f) - z * y[w] + log1pf(expf(-fabsf(z)));
    }
    __syncthreads();
    if (threadIdx.x == 0) {
        float L = 0.f;
        for (int g2 = 0; g2 < 16; ++g2) L += lloss[g2];
        out[0] = L * (1.f / 16.f);
    }
}

extern "C" void kernel_launch(void* const* d_in, const int* in_sizes, int n_in,
                              void* d_out, int out_size, void* d_ws, size_t ws_size,
                              hipStream_t stream) {
    const int* word_id   = (const int*)d_in[0];
    const int* topic_id  = (const int*)d_in[1];
    const int* g_word    = (const int*)d_in[2];
    const int* g_topic   = (const int*)d_in[3];
    const int* g_doc     = (const int*)d_in[4];
    const int* src_ww = (const int*)d_in[5];  const int* dst_ww = (const int*)d_in[6];  const int* time_ww = (const int*)d_in[7];
    const int* src_wd = (const int*)d_in[8];  const int* dst_wd = (const int*)d_in[9];  const int* time_wd = (const int*)d_in[10];
    const int* src_wt = (const int*)d_in[11]; const int* dst_wt = (const int*)d_in[12]; const int* time_wt = (const int*)d_in[13];
    const int* src_td = (const int*)d_in[14]; const int* dst_td = (const int*)d_in[15]; const int* time_td = (const int*)d_in[16];
    const int* src_tt = (const int*)d_in[17]; const int* dst_tt = (const int*)d_in[18];
    const float* y_data      = (const float*)d_in[19];
    const float* word_embeds = (const float*)d_in[20];
    const float* topic_embeds= (const float*)d_in[21];
    const float* doc_gen     = (const float*)d_in[22];
    const float* adapt_w     = (const float*)d_in[23];
    const float* adapt_b     = (const float*)d_in[24];
    const float* time_tab    = (const float*)d_in[25];
    const float* time_w      = (const float*)d_in[26];
    const float* time_b      = (const float*)d_in[27];
    const float* kW = (const float*)d_in[28];
    const float* qW = (const float*)d_in[29];
    const float* vW = (const float*)d_in[30];
    const float* aW = (const float*)d_in[31];
    const float* kB = (const float*)d_in[32];
    const float* qB = (const float*)d_in[33];
    const float* vB = (const float*)d_in[34];
    const float* aB = (const float*)d_in[35];
    const float* skip = (const float*)d_in[36];
    const float* ln_g = (const float*)d_in[37];
    const float* ln_b = (const float*)d_in[38];
    const float* pri  = (const float*)d_in[39];
    const float* attR = (const float*)d_in[40];
    const float* msgR = (const float*)d_in[41];
    const float* out_w = (const float*)d_in[42];
    const float* out_b = (const float*)d_in[43];

    const int NW = in_sizes[0], NT = in_sizes[1], ND = in_sizes[4];
    const int E_ww = in_sizes[5], E_wd = in_sizes[8], E_wt = in_sizes[11],
              E_td = in_sizes[14], E_tt = in_sizes[17];
    const int nN[3] = {NW, NT, ND};
    const float invNin[3] = {1.f / 3.f, 1.f / 3.f, 1.f / 2.f};

    struct Rel { int e, s, d; const int* src; const int* dst; const int* tim; int E; };
    const Rel rels[8] = {
        {0, 0, 1, src_wt, dst_wt, time_wt, E_wt},
        {1, 0, 2, src_wd, dst_wd, time_wd, E_wd},
        {2, 1, 2, src_td, dst_td, time_td, E_td},
        {3, 1, 1, src_tt, dst_tt, nullptr, E_tt},
        {4, 0, 0, src_ww, dst_ww, time_ww, E_ww},
        {5, 1, 0, dst_wt, src_wt, time_wt, E_wt},
        {6, 2, 1, dst_td, src_td, time_td, E_td},
        {7, 2, 0, dst_wd, src_wd, time_wd, E_wd},
    };

    int relOfs[9]; relOfs[0] = 0;
    int dstBase[8]; int acc = 0;
    for (int r = 0; r < 8; ++r) { relOfs[r + 1] = relOfs[r] + rels[r].E; dstBase[r] = acc; acc += nN[rels[r].d]; }
    const int totE = relOfs[8], totD = acc;

    const int grpRels[3][3] = {{4, 5, 7}, {0, 3, 6}, {1, 2, 0}};
    const int nrG[3] = {3, 3, 2};
    int rowOfsG[3][3], grpRows[3];
    for (int g = 0; g < 3; ++g) {
        int ro = 0;
        for (int j = 0; j < nrG[g]; ++j) { rowOfsG[g][j] = ro; ro += nN[rels[grpRels[g][j]].s]; }
        grpRows[g] = ro;
    }
    int maxGrpRows = 0;
    for (int g = 0; g < 3; ++g) if (grpRows[g] > maxGrpRows) maxGrpRows = grpRows[g];

    float* base = (float*)d_ws;
    size_t off = 0;
    auto take = [&](size_t nElems) { float* p = base + off; off += (nElems + 63) & ~(size_t)63; return p; };
    float* hP[3]; float* tP[3];
    unsigned short* kP[3]; unsigned short* qP[3]; unsigned short* vP[3];
    for (int i = 0; i < 3; ++i) hP[i] = take((size_t)nN[i] * 256);
    for (int i = 0; i < 3; ++i) tP[i] = take((size_t)nN[i] * 256);
    for (int i = 0; i < 3; ++i) kP[i] = (unsigned short*)take((size_t)nN[i] * 128);
    for (int i = 0; i < 3; ++i) qP[i] = (unsigned short*)take((size_t)nN[i] * 128);
    for (int i = 0; i < 3; ++i) vP[i] = (unsigned short*)take((size_t)nN[i] * 128);
    unsigned short* kattB = (unsigned short*)take((size_t)maxGrpRows * 128);
    unsigned short* vmsgB = (unsigned short*)take((size_t)maxGrpRows * 128);
    float* trans = (float*)kattB;
    unsigned short* WT = (unsigned short*)take((size_t)25 * 32768);
    float* alog = take((size_t)totE * 8);
    float* te7  = take(7 * 32);
    unsigned* gi = (unsigned*)take(16 * 768);
    int* cntAll = (int*)take(totD);
    int* part   = (int*)take(totD);
    int* bsum   = (int*)take(256);
    int* rowptrAll = (int*)take(totD + 1);
    int* curAll = (int*)take(totD);
    int* eidxAll = (int*)take(totE);
    (void)ws_size; (void)n_in; (void)out_size;

    te_kernel<<<1, 256, 0, stream>>>(time_tab, time_w, time_b, te7);
    {
        dim3 g(8, 8, 25);
        wtr_kernel<<<g, 256, 0, stream>>>(adapt_w, kW, qW, vW, aW, WT);
    }
    CsrArgs ca;
    for (int r = 0; r < 8; ++r) { ca.dst[r] = rels[r].dst; ca.dstBase[r] = dstBase[r]; }
    for (int r = 0; r < 9; ++r) ca.relOfs[r] = relOfs[r];
    hipMemsetAsync(cntAll, 0, (size_t)totD * sizeof(int), stream);
    count_all<<<(totE + 255) / 256, 256, 0, stream>>>(ca, cntAll, totE);
    int nb = (totD + 1023) / 1024;
    scan1_k<<<nb, 1024, 0, stream>>>(cntAll, part, bsum, totD);
    scan2_k<<<1, 256, 0, stream>>>(bsum, nb);
    scan3_k<<<(totD + 255) / 256, 256, 0, stream>>>(cntAll, part, bsum, rowptrAll, curAll, totD);
    scatter_all<<<(totE + 255) / 256, 256, 0, stream>>>(ca, curAll, eidxAll, totE);
    gi_init<<<48, 256, 0, stream>>>(gi);

    {
        dim3 g((NW + 63) / 64, 4, 1);
        gemm_mfma<<<g, 256, 0, stream>>>(word_embeds, word_id, WT, 0,
                                         adapt_b, adapt_b, adapt_b,
                                         hP[0], hP[0], hP[0], NW, 1.f, 0);
    }
    gather_rows<<<NT, 256, 0, stream>>>(topic_embeds, topic_id, hP[1], NT);
    bcast_row<<<ND, 256, 0, stream>>>(doc_gen, hP[2], ND);

    Ek1Args e1a[3]; Ek3Args e3a[3];
    int maxE_g[3];
    for (int g = 0; g < 3; ++g) {
        int me = 0;
        for (int j = 0; j < 3; ++j) {
            int jr = (j < nrG[g]) ? grpRels[g][j] : grpRels[g][0];
            const Rel& R = rels[jr];
            e1a[g].src[j] = R.src; e1a[g].dst[j] = R.dst;
            e1a[g].E[j] = (j < nrG[g]) ? R.E : 0;
            e1a[g].eBase[j] = relOfs[jr];
            e1a[g].rowOfs[j] = (j < nrG[g]) ? rowOfsG[g][j] : 0;
            e3a[g].src[j] = R.src; e3a[g].tim[j] = R.tim;
            e3a[g].eBase[j] = relOfs[jr]; e3a[g].dstBase[j] = dstBase[jr];
            e3a[g].rowOfs[j] = (j < nrG[g]) ? rowOfsG[g][j] : 0;
            if (j < nrG[g] && R.E > me) me = R.E;
        }
        e3a[g].nr = nrG[g]; e3a[g].nD = nN[g];
        maxE_g[g] = me;
    }

    for (int li = 0; li < LNUM; ++li) {
        for (int i = 0; i < 3; ++i) {
            int j = li * 3 + i;
            dim3 g((nN[i] + 63) / 64, 4, 3);
            gemm_mfma<<<g, 256, 0, stream>>>(hP[i], nullptr, WT + (size_t)(1 + j) * 65536, 6 * 65536,
                                             kB + (size_t)j * 256, qB + (size_t)j * 256, vB + (size_t)j * 256,
                                             kP[i], qP[i], vP[i], nN[i], 1.f, 1);
        }

        for (int g = 0; g < 3; ++g) {
            BdArgs ba;
            int maxRows = 0;
            for (int j = 0; j < 3; ++j) {
                int jr = (j < nrG[g]) ? grpRels[g][j] : grpRels[g][0];
                const Rel& R = rels[jr];
                ba.inK[j] = kP[R.s]; ba.inV[j] = vP[R.s];
                ba.RA[j] = attR + ((size_t)li * 8 + R.e) * 8192;
                ba.RM[j] = msgR + ((size_t)li * 8 + R.e) * 8192;
                ba.priP[j] = pri + ((size_t)li * 8 + R.e) * 8;
                ba.rows[j] = (j < nrG[g]) ? nN[R.s] : 0;
                ba.rowOfs[j] = (j < nrG[g]) ? rowOfsG[g][j] : 0;
                if (ba.rows[j] > maxRows) maxRows = ba.rows[j];
            }
            dim3 gb((maxRows + 63) / 64, 8, 2 * nrG[g]);
            bd_group<<<gb, 256, 0, stream>>>(kattB, vmsgB, ba);
            dim3 g1((maxE_g[g] * 8 + 255) / 256, nrG[g]);
            ek1_group<<<g1, 256, 0, stream>>>(qP[g], kattB, alog, e1a[g]);
            ek3_group<<<(nN[g] + 3) / 4, 256, 0, stream>>>(vmsgB, alog, rowptrAll, eidxAll,
                                                           te7, tP[g], e3a[g]);
        }

        for (int i = 0; i < 3; ++i) {
            int j = li * 3 + i;
            dim3 g((nN[i] + 63) / 64, 4, 1);
            gemm_mfma<<<g, 256, 0, stream>>>(tP[i], nullptr, WT + (size_t)(19 + j) * 65536, 0,
                                             aB + (size_t)j * 256, aB + (size_t)j * 256, aB + (size_t)j * 256,
                                             trans, trans, trans, nN[i], invNin[i], 0);
            mix_ln<<<nN[i], 256, 0, stream>>>(hP[i], trans, skip + (size_t)j,
                                              ln_g + (size_t)j * 256, ln_b + (size_t)j * 256, nN[i]);
        }
    }

    GmaxArgs ga;
    ga.hp[0] = hP[2]; ga.grp[0] = g_doc;   ga.n[0] = ND; ga.colBase[0] = 0;
    ga.hp[1] = hP[0]; ga.grp[1] = g_word;  ga.n[1] = NW; ga.colBase[1] = 256;
    ga.hp[2] = hP[1]; ga.grp[2] = g_topic; ga.n[2] = NT; ga.colBase[2] = 512;
    int maxN = NW > ND ? (NW > NT ? NW : NT) : (ND > NT ? ND : NT);
    dim3 gg((maxN + 63) / 64, 3);
    gmax_all<<<gg, 256, 0, stream>>>(ga, gi);
    final_k<<<1, 1024, 0, stream>>>(gi, out_w, out_b, y_data, (float*)d_out);
}